// Round 1
// baseline (262.608 us; speedup 1.0000x reference)
//
#include <hip/hip_runtime.h>
#include <hip/hip_bf16.h>
#include <cstdint>

#define B_  8
#define SQ_ 1024
#define SK_ 1024
#define D_  768
#define H_  12
#define HD_ 64

typedef __attribute__((ext_vector_type(8))) short s16x8;
typedef __attribute__((ext_vector_type(4))) float f32x4;

__device__ __forceinline__ float bf2f(ushort u) {
    union { uint32_t i; float f; } v; v.i = ((uint32_t)u) << 16; return v.f;
}
__device__ __forceinline__ ushort f2bf(float f) {
    union { float f; uint32_t i; } v; v.f = f;
    uint32_t x = v.i;
    return (ushort)((x + 0x7fffu + ((x >> 16) & 1u)) >> 16);  // RNE; inputs finite
}

// ---------------- convert f32 -> bf16 (vectorized) ----------------
__global__ void convX(const float4* __restrict__ src, ushort* __restrict__ dst, int n4) {
    int i = blockIdx.x * blockDim.x + threadIdx.x;
    int stride = gridDim.x * blockDim.x;
    for (; i < n4; i += stride) {
        float4 v = src[i];
        ushort4 o = { f2bf(v.x), f2bf(v.y), f2bf(v.z), f2bf(v.w) };
        *reinterpret_cast<ushort4*>(dst + (size_t)i * 4) = o;
    }
}

// ---------------- convert + transpose W[k][n] f32 -> WT[n][k] bf16 ----------------
__global__ void convWT(const float* __restrict__ W, ushort* __restrict__ WT) {
    __shared__ float t[32][33];
    int k0 = blockIdx.x * 32, n0 = blockIdx.y * 32;
    int tx = threadIdx.x & 31, ty = threadIdx.x >> 5;  // 32 x 8
#pragma unroll
    for (int rr = 0; rr < 4; ++rr)
        t[ty + 8 * rr][tx] = W[(size_t)(k0 + ty + 8 * rr) * D_ + n0 + tx];
    __syncthreads();
#pragma unroll
    for (int rr = 0; rr < 4; ++rr)
        WT[(size_t)(n0 + ty + 8 * rr) * D_ + k0 + tx] = f2bf(t[tx][ty + 8 * rr]);
}

// ---------------- QKV GEMM: C = A(bf16)[M][K] * WT(bf16)[N][K]^T + bias ----------------
#define GL16(g, l)                                                                     \
    __builtin_amdgcn_global_load_lds((const __attribute__((address_space(1))) void*)(g), \
                                     (__attribute__((address_space(3))) void*)(l), 16, 0, 0)

__global__ __launch_bounds__(256) void gemm_qkv(
    const ushort* __restrict__ hb, const ushort* __restrict__ cb,
    const ushort* __restrict__ wqt, const ushort* __restrict__ wkt, const ushort* __restrict__ wvt,
    const float* __restrict__ bq, const float* __restrict__ bk, const float* __restrict__ bv,
    ushort* __restrict__ qout, ushort* __restrict__ kout, ushort* __restrict__ vtout)
{
    const int z = blockIdx.z;
    const ushort* A    = (z == 0) ? hb : cb;
    const ushort* Wt   = (z == 0) ? wqt : (z == 1) ? wkt : wvt;
    const float*  bias = (z == 0) ? bq  : (z == 1) ? bk  : bv;

    __shared__ ushort As[128 * 32];
    __shared__ ushort Bs[128 * 32];

    const int tid = threadIdx.x;
    const int w = tid >> 6, l = tid & 63;
    const int g = l >> 4, c = l & 15;
    const int wr = w >> 1, wc = w & 1;
    const int m0 = blockIdx.x * 128;
    const int n0 = blockIdx.y * 128;

    f32x4 acc[4][4];
#pragma unroll
    for (int mi = 0; mi < 4; ++mi)
#pragma unroll
        for (int ni = 0; ni < 4; ++ni) acc[mi][ni] = (f32x4){0.f, 0.f, 0.f, 0.f};

    for (int kt = 0; kt < D_ / 32; ++kt) {
        __syncthreads();
#pragma unroll
        for (int j = 0; j < 2; ++j) {
            int cc = (j * 4 + w) * 64 + l;     // chunk 0..511, 16B each
            int row = cc >> 2, c8 = cc & 3;    // tile row, 16B-chunk within row
            const ushort* ga = A  + (size_t)(m0 + row) * D_ + kt * 32 + c8 * 8;
            GL16(ga, (char*)As + (size_t)(j * 4 + w) * 1024);
            const ushort* gb = Wt + (size_t)(n0 + row) * D_ + kt * 32 + c8 * 8;
            GL16(gb, (char*)Bs + (size_t)(j * 4 + w) * 1024);
        }
        __syncthreads();

        s16x8 af[4], bfr[4];
#pragma unroll
        for (int mi = 0; mi < 4; ++mi)
            af[mi] = *(const s16x8*)&As[(wr * 64 + mi * 16 + c) * 32 + g * 8];
#pragma unroll
        for (int ni = 0; ni < 4; ++ni)
            bfr[ni] = *(const s16x8*)&Bs[(wc * 64 + ni * 16 + c) * 32 + g * 8];
#pragma unroll
        for (int mi = 0; mi < 4; ++mi)
#pragma unroll
            for (int ni = 0; ni < 4; ++ni)
                acc[mi][ni] = __builtin_amdgcn_mfma_f32_16x16x32_bf16(af[mi], bfr[ni], acc[mi][ni], 0, 0, 0);
    }

    if (z < 2) {
        ushort* Out = (z == 0) ? qout : kout;
#pragma unroll
        for (int ni = 0; ni < 4; ++ni) {
            int ncol = n0 + wc * 64 + ni * 16 + c;
            float bv_ = bias[ncol];
#pragma unroll
            for (int mi = 0; mi < 4; ++mi) {
#pragma unroll
                for (int r = 0; r < 4; ++r) {
                    int mrow = m0 + wr * 64 + mi * 16 + 4 * g + r;
                    Out[(size_t)mrow * D_ + ncol] = f2bf(acc[mi][ni][r] + bv_);
                }
            }
        }
    } else {
        // V: write transposed per-head: VT[((b*H + h)*HD + d)*SK + s]
#pragma unroll
        for (int ni = 0; ni < 4; ++ni) {
            int ncol = n0 + wc * 64 + ni * 16 + c;
            float bv_ = bias[ncol];
            int hh = ncol >> 6, dd = ncol & 63;
#pragma unroll
            for (int mi = 0; mi < 4; ++mi) {
                int mrow = m0 + wr * 64 + mi * 16 + 4 * g;   // 4 consecutive rows
                int bb = mrow >> 10, ss = mrow & 1023;
                ushort4 pk;
                pk.x = f2bf(acc[mi][ni][0] + bv_);
                pk.y = f2bf(acc[mi][ni][1] + bv_);
                pk.z = f2bf(acc[mi][ni][2] + bv_);
                pk.w = f2bf(acc[mi][ni][3] + bv_);
                *reinterpret_cast<ushort4*>(vtout + (size_t)((bb * H_ + hh) * HD_ + dd) * SK_ + ss) = pk;
            }
        }
    }
}

// ---------------- flash attention ----------------
__global__ __launch_bounds__(256) void attn(
    const ushort* __restrict__ Qb, const ushort* __restrict__ Kb, const ushort* __restrict__ VT,
    const float* __restrict__ amask, float* __restrict__ out)
{
    __shared__ ushort Ks[64 * 64];
    __shared__ ushort Vs[64 * 64];      // holds V^T tile: row = d, col = kv
    __shared__ ushort Ps[4][16 * 64];   // per-wave P tile

    const int tid = threadIdx.x;
    const int w = tid >> 6, l = tid & 63;
    const int g = l >> 4, c = l & 15;
    const int q0 = blockIdx.x * 64;
    const int h  = blockIdx.y;
    const int b  = blockIdx.z;

    // Q fragments (pre-scaled by 1/sqrt(64) = 0.125, exact in bf16)
    s16x8 qf[2];
#pragma unroll
    for (int kk = 0; kk < 2; ++kk) {
        const ushort* gq = Qb + (size_t)(b * SQ_ + q0 + w * 16 + c) * D_ + h * HD_ + kk * 32 + g * 8;
        s16x8 v = *(const s16x8*)gq;
#pragma unroll
        for (int i = 0; i < 8; ++i) v[i] = (short)f2bf(bf2f((ushort)v[i]) * 0.125f);
        qf[kk] = v;
    }

    f32x4 o[4];
#pragma unroll
    for (int nn = 0; nn < 4; ++nn) o[nn] = (f32x4){0.f, 0.f, 0.f, 0.f};
    float m_run[4], l_run[4];
#pragma unroll
    for (int r = 0; r < 4; ++r) { m_run[r] = -INFINITY; l_run[r] = 0.f; }

    const float L2E = 1.44269504f;

    for (int t = 0; t < SK_ / 64; ++t) {
        const int kv0 = t * 64;
        __syncthreads();
        // stage K tile [64 kv][64 d] and V^T tile [64 d][64 kv], XOR-swizzled
#pragma unroll
        for (int j = 0; j < 2; ++j) {
            int cc = j * 256 + tid;
            int row = cc >> 3, c8 = cc & 7;
            int ldsb = row * 128 + ((c8 * 16) ^ ((row & 7) << 4));
            uint4 kv_ = *(const uint4*)(Kb + (size_t)(b * SK_ + kv0 + row) * D_ + h * HD_ + c8 * 8);
            *(uint4*)((char*)Ks + ldsb) = kv_;
            uint4 vv_ = *(const uint4*)(VT + (size_t)((b * H_ + h) * HD_ + row) * SK_ + kv0 + c8 * 8);
            *(uint4*)((char*)Vs + ldsb) = vv_;
        }
        __syncthreads();

        // S = Q * K^T  (rows = q (4g+r), cols = kv (16n+c))
        float sv[4][4];
#pragma unroll
        for (int n = 0; n < 4; ++n) {
            f32x4 s = (f32x4){0.f, 0.f, 0.f, 0.f};
#pragma unroll
            for (int kk = 0; kk < 2; ++kk) {
                const s16x8 bf_ = *(const s16x8*)((const char*)Ks + (16 * n + c) * 128 +
                                                  ((kk * 64 + g * 16) ^ ((c & 7) << 4)));
                s = __builtin_amdgcn_mfma_f32_16x16x32_bf16(qf[kk], bf_, s, 0, 0, 0);
            }
            float mv = amask[b * SK_ + kv0 + 16 * n + c];
#pragma unroll
            for (int r = 0; r < 4; ++r) sv[n][r] = s[r] + mv;
        }

        // online softmax over the 64 kv columns of this tile
        float rmax[4], alpha[4], rsum[4];
#pragma unroll
        for (int r = 0; r < 4; ++r) {
            rmax[r] = fmaxf(fmaxf(sv[0][r], sv[1][r]), fmaxf(sv[2][r], sv[3][r]));
            rmax[r] = fmaxf(rmax[r], __shfl_xor(rmax[r], 1));
            rmax[r] = fmaxf(rmax[r], __shfl_xor(rmax[r], 2));
            rmax[r] = fmaxf(rmax[r], __shfl_xor(rmax[r], 4));
            rmax[r] = fmaxf(rmax[r], __shfl_xor(rmax[r], 8));
        }
#pragma unroll
        for (int r = 0; r < 4; ++r) {
            float mn = fmaxf(m_run[r], rmax[r]);
            alpha[r] = exp2f((m_run[r] - mn) * L2E);
            m_run[r] = mn;
            rsum[r] = 0.f;
        }
#pragma unroll
        for (int n = 0; n < 4; ++n)
#pragma unroll
            for (int r = 0; r < 4; ++r) {
                float p = exp2f((sv[n][r] - m_run[r]) * L2E);
                sv[n][r] = p;
                rsum[r] += p;
            }
#pragma unroll
        for (int r = 0; r < 4; ++r) {
            rsum[r] += __shfl_xor(rsum[r], 1);
            rsum[r] += __shfl_xor(rsum[r], 2);
            rsum[r] += __shfl_xor(rsum[r], 4);
            rsum[r] += __shfl_xor(rsum[r], 8);
            l_run[r] = l_run[r] * alpha[r] + rsum[r];
        }
#pragma unroll
        for (int nn = 0; nn < 4; ++nn)
#pragma unroll
            for (int r = 0; r < 4; ++r) o[nn][r] *= alpha[r];

        // P -> bf16 -> per-wave LDS (swizzled), then re-read as A-fragments
#pragma unroll
        for (int n = 0; n < 4; ++n)
#pragma unroll
            for (int r = 0; r < 4; ++r) {
                int row = 4 * g + r;
                *(ushort*)((char*)&Ps[w][0] + row * 128 +
                           (((16 * n + c) * 2) ^ ((row & 7) << 4))) = f2bf(sv[n][r]);
            }
        s16x8 pa[2];
#pragma unroll
        for (int kk = 0; kk < 2; ++kk)
            pa[kk] = *(const s16x8*)((const char*)&Ps[w][0] + c * 128 +
                                     ((kk * 64 + g * 16) ^ ((c & 7) << 4)));
#pragma unroll
        for (int nn = 0; nn < 4; ++nn) {
#pragma unroll
            for (int kk = 0; kk < 2; ++kk) {
                const s16x8 bv_ = *(const s16x8*)((const char*)Vs + (16 * nn + c) * 128 +
                                                  ((kk * 64 + g * 16) ^ ((c & 7) << 4)));
                o[nn] = __builtin_amdgcn_mfma_f32_16x16x32_bf16(pa[kk], bv_, o[nn], 0, 0, 0);
            }
        }
    }

    // epilogue: out[b][q][h*64+d] = o / l_run
    float inv[4];
#pragma unroll
    for (int r = 0; r < 4; ++r) inv[r] = 1.f / l_run[r];
#pragma unroll
    for (int nn = 0; nn < 4; ++nn)
#pragma unroll
        for (int r = 0; r < 4; ++r)
            out[(size_t)(b * SQ_ + q0 + w * 16 + 4 * g + r) * D_ + h * HD_ + 16 * nn + c] =
                o[nn][r] * inv[r];
}

extern "C" void kernel_launch(void* const* d_in, const int* in_sizes, int n_in,
                              void* d_out, int out_size, void* d_ws, size_t ws_size,
                              hipStream_t stream) {
    (void)in_sizes; (void)n_in; (void)out_size; (void)ws_size;
    const float* hidden  = (const float*)d_in[0];
    const float* context = (const float*)d_in[1];
    const float* amask   = (const float*)d_in[2];
    const float* Wq = (const float*)d_in[3];
    const float* bq = (const float*)d_in[4];
    const float* Wk = (const float*)d_in[5];
    const float* bk = (const float*)d_in[6];
    const float* Wv = (const float*)d_in[7];
    const float* bv = (const float*)d_in[8];
    float* out = (float*)d_out;

    char* ws = (char*)d_ws;
    ushort* hb  = (ushort*)(ws);              // 12.6 MB  hidden bf16 [8192][768]
    ushort* cb  = (ushort*)(ws + 12582912);   // 12.6 MB  context bf16
    ushort* wqt = (ushort*)(ws + 25165824);   // 1.18 MB  Wq^T bf16 [768][768]
    ushort* wkt = (ushort*)(ws + 26345472);
    ushort* wvt = (ushort*)(ws + 27525120);
    ushort* qb  = (ushort*)(ws + 28704768);   // 12.6 MB  Q bf16 [8192][768]
    ushort* kb  = (ushort*)(ws + 41287680);   // 12.6 MB  K bf16 [8192][768]
    ushort* vt  = (ushort*)(ws + 53870592);   // 12.6 MB  V^T bf16 [B][H][64][1024]
    // total 66,453,504 bytes

    int n4 = (B_ * SQ_ * D_) / 4;
    convX<<<2048, 256, 0, stream>>>((const float4*)hidden, hb, n4);
    convX<<<2048, 256, 0, stream>>>((const float4*)context, cb, n4);
    dim3 gw(24, 24);
    convWT<<<gw, 256, 0, stream>>>(Wq, wqt);
    convWT<<<gw, 256, 0, stream>>>(Wk, wkt);
    convWT<<<gw, 256, 0, stream>>>(Wv, wvt);
    gemm_qkv<<<dim3(64, 6, 3), 256, 0, stream>>>(hb, cb, wqt, wkt, wvt, bq, bk, bv, qb, kb, vt);
    attn<<<dim3(16, 12, 8), 256, 0, stream>>>(qb, kb, vt, amask, out);
}

// Round 3
// 238.067 us; speedup vs baseline: 1.1031x; 1.1031x over previous
//
#include <hip/hip_runtime.h>
#include <hip/hip_bf16.h>
#include <cstdint>

#define B_  8
#define SQ_ 1024
#define SK_ 1024
#define D_  768
#define H_  12
#define HD_ 64

typedef __attribute__((ext_vector_type(8))) short s16x8;
typedef __attribute__((ext_vector_type(4))) float f32x4;

__device__ __forceinline__ float bf2f(ushort u) {
    union { uint32_t i; float f; } v; v.i = ((uint32_t)u) << 16; return v.f;
}
// HW convert: compiler lowers the plain cast to v_cvt_pk_bf16_f32 on gfx950
// (learn_hip m240: scalar cast beats hand-written inline-asm cvt_pk).
__device__ __forceinline__ ushort f2bf(float f) {
    __hip_bfloat16 h = __float2bfloat16(f);
    union { __hip_bfloat16 h; ushort u; } v; v.h = h; return v.u;
}

// ---------------- convert f32 -> bf16 (vectorized) ----------------
__global__ void convX(const float4* __restrict__ src, ushort* __restrict__ dst, int n4) {
    int i = blockIdx.x * blockDim.x + threadIdx.x;
    int stride = gridDim.x * blockDim.x;
    for (; i < n4; i += stride) {
        float4 v = src[i];
        ushort4 o = { f2bf(v.x), f2bf(v.y), f2bf(v.z), f2bf(v.w) };
        *reinterpret_cast<ushort4*>(dst + (size_t)i * 4) = o;
    }
}

// ---------------- convert + transpose W[k][n] f32 -> WT[n][k] bf16 ----------------
__global__ void convWT(const float* __restrict__ W, ushort* __restrict__ WT) {
    __shared__ float t[32][33];
    int k0 = blockIdx.x * 32, n0 = blockIdx.y * 32;
    int tx = threadIdx.x & 31, ty = threadIdx.x >> 5;  // 32 x 8
#pragma unroll
    for (int rr = 0; rr < 4; ++rr)
        t[ty + 8 * rr][tx] = W[(size_t)(k0 + ty + 8 * rr) * D_ + n0 + tx];
    __syncthreads();
#pragma unroll
    for (int rr = 0; rr < 4; ++rr)
        WT[(size_t)(n0 + ty + 8 * rr) * D_ + k0 + tx] = f2bf(t[tx][ty + 8 * rr]);
}

// ---------------- QKV GEMM: C = A(bf16)[M][K] * WT(bf16)[N][K]^T + bias ----------------
#define GL16(g, l)                                                                     \
    __builtin_amdgcn_global_load_lds((const __attribute__((address_space(1))) void*)(g), \
                                     (__attribute__((address_space(3))) void*)(l), 16, 0, 0)

__global__ __launch_bounds__(256) void gemm_qkv(
    const ushort* __restrict__ hb, const ushort* __restrict__ cb,
    const ushort* __restrict__ wqt, const ushort* __restrict__ wkt, const ushort* __restrict__ wvt,
    const float* __restrict__ bq, const float* __restrict__ bk, const float* __restrict__ bv,
    ushort* __restrict__ qout, ushort* __restrict__ kout, ushort* __restrict__ vtout)
{
    const int z = blockIdx.z;
    const ushort* A    = (z == 0) ? hb : cb;
    const ushort* Wt   = (z == 0) ? wqt : (z == 1) ? wkt : wvt;
    const float*  bias = (z == 0) ? bq  : (z == 1) ? bk  : bv;

    __shared__ ushort As[128 * 32];
    __shared__ ushort Bs[128 * 32];

    const int tid = threadIdx.x;
    const int w = tid >> 6, l = tid & 63;
    const int g = l >> 4, c = l & 15;
    const int wr = w >> 1, wc = w & 1;
    const int m0 = blockIdx.x * 128;
    const int n0 = blockIdx.y * 128;

    f32x4 acc[4][4];
#pragma unroll
    for (int mi = 0; mi < 4; ++mi)
#pragma unroll
        for (int ni = 0; ni < 4; ++ni) acc[mi][ni] = (f32x4){0.f, 0.f, 0.f, 0.f};

    for (int kt = 0; kt < D_ / 32; ++kt) {
        __syncthreads();
#pragma unroll
        for (int j = 0; j < 2; ++j) {
            int cc = (j * 4 + w) * 64 + l;     // chunk 0..511, 16B each
            int row = cc >> 2, c8 = cc & 3;    // tile row, 16B-chunk within row
            const ushort* ga = A  + (size_t)(m0 + row) * D_ + kt * 32 + c8 * 8;
            GL16(ga, (char*)As + (size_t)(j * 4 + w) * 1024);
            const ushort* gb = Wt + (size_t)(n0 + row) * D_ + kt * 32 + c8 * 8;
            GL16(gb, (char*)Bs + (size_t)(j * 4 + w) * 1024);
        }
        __syncthreads();

        s16x8 af[4], bfr[4];
#pragma unroll
        for (int mi = 0; mi < 4; ++mi)
            af[mi] = *(const s16x8*)&As[(wr * 64 + mi * 16 + c) * 32 + g * 8];
#pragma unroll
        for (int ni = 0; ni < 4; ++ni)
            bfr[ni] = *(const s16x8*)&Bs[(wc * 64 + ni * 16 + c) * 32 + g * 8];
#pragma unroll
        for (int mi = 0; mi < 4; ++mi)
#pragma unroll
            for (int ni = 0; ni < 4; ++ni)
                acc[mi][ni] = __builtin_amdgcn_mfma_f32_16x16x32_bf16(af[mi], bfr[ni], acc[mi][ni], 0, 0, 0);
    }

    if (z < 2) {
        ushort* Out = (z == 0) ? qout : kout;
#pragma unroll
        for (int ni = 0; ni < 4; ++ni) {
            int ncol = n0 + wc * 64 + ni * 16 + c;
            float bv_ = bias[ncol];
#pragma unroll
            for (int mi = 0; mi < 4; ++mi) {
#pragma unroll
                for (int r = 0; r < 4; ++r) {
                    int mrow = m0 + wr * 64 + mi * 16 + 4 * g + r;
                    Out[(size_t)mrow * D_ + ncol] = f2bf(acc[mi][ni][r] + bv_);
                }
            }
        }
    } else {
        // V: write transposed per-head: VT[((b*H + h)*HD + d)*SK + s]
#pragma unroll
        for (int ni = 0; ni < 4; ++ni) {
            int ncol = n0 + wc * 64 + ni * 16 + c;
            float bv_ = bias[ncol];
            int hh = ncol >> 6, dd = ncol & 63;
#pragma unroll
            for (int mi = 0; mi < 4; ++mi) {
                int mrow = m0 + wr * 64 + mi * 16 + 4 * g;   // 4 consecutive rows
                int bb = mrow >> 10, ss = mrow & 1023;
                ushort4 pk;
                pk.x = f2bf(acc[mi][ni][0] + bv_);
                pk.y = f2bf(acc[mi][ni][1] + bv_);
                pk.z = f2bf(acc[mi][ni][2] + bv_);
                pk.w = f2bf(acc[mi][ni][3] + bv_);
                *reinterpret_cast<ushort4*>(vtout + (size_t)((bb * H_ + hh) * HD_ + dd) * SK_ + ss) = pk;
            }
        }
    }
}

// ---------------- flash attention ----------------
__global__ __launch_bounds__(256) void attn(
    const ushort* __restrict__ Qb, const ushort* __restrict__ Kb, const ushort* __restrict__ VT,
    const float* __restrict__ amask, float* __restrict__ out)
{
    __shared__ ushort Ks[64 * 64];
    __shared__ ushort Vs[64 * 64];      // holds V^T tile: row = d, col = kv
    __shared__ ushort Ps[4][16 * 64];   // per-wave P tile

    const int tid = threadIdx.x;
    const int w = tid >> 6, l = tid & 63;
    const int g = l >> 4, c = l & 15;
    const int q0 = blockIdx.x * 64;
    const int h  = blockIdx.y;
    const int b  = blockIdx.z;

    // Q fragments (pre-scaled by 1/sqrt(64) = 0.125, exact in bf16)
    s16x8 qf[2];
#pragma unroll
    for (int kk = 0; kk < 2; ++kk) {
        const ushort* gq = Qb + (size_t)(b * SQ_ + q0 + w * 16 + c) * D_ + h * HD_ + kk * 32 + g * 8;
        s16x8 v = *(const s16x8*)gq;
#pragma unroll
        for (int i = 0; i < 8; ++i) v[i] = (short)f2bf(bf2f((ushort)v[i]) * 0.125f);
        qf[kk] = v;
    }

    f32x4 o[4];
#pragma unroll
    for (int nn = 0; nn < 4; ++nn) o[nn] = (f32x4){0.f, 0.f, 0.f, 0.f};
    float m_run[4], ps[4];
#pragma unroll
    for (int r = 0; r < 4; ++r) { m_run[r] = -INFINITY; ps[r] = 0.f; }

    const float L2E = 1.44269504f;

    for (int t = 0; t < SK_ / 64; ++t) {
        const int kv0 = t * 64;
        __syncthreads();
        // stage K tile [64 kv][64 d] and V^T tile [64 d][64 kv], XOR-swizzled
#pragma unroll
        for (int j = 0; j < 2; ++j) {
            int cc = j * 256 + tid;
            int row = cc >> 3, c8 = cc & 7;
            int ldsb = row * 128 + ((c8 * 16) ^ ((row & 7) << 4));
            uint4 kv_ = *(const uint4*)(Kb + (size_t)(b * SK_ + kv0 + row) * D_ + h * HD_ + c8 * 8);
            *(uint4*)((char*)Ks + ldsb) = kv_;
            uint4 vv_ = *(const uint4*)(VT + (size_t)((b * H_ + h) * HD_ + row) * SK_ + kv0 + c8 * 8);
            *(uint4*)((char*)Vs + ldsb) = vv_;
        }
        __syncthreads();

        // S = Q * K^T  (rows = q (4g+r), cols = kv (16n+c))
        float sv[4][4];
#pragma unroll
        for (int n = 0; n < 4; ++n) {
            f32x4 s = (f32x4){0.f, 0.f, 0.f, 0.f};
#pragma unroll
            for (int kk = 0; kk < 2; ++kk) {
                const s16x8 bf_ = *(const s16x8*)((const char*)Ks + (16 * n + c) * 128 +
                                                  ((kk * 64 + g * 16) ^ ((c & 7) << 4)));
                s = __builtin_amdgcn_mfma_f32_16x16x32_bf16(qf[kk], bf_, s, 0, 0, 0);
            }
            float mv = amask[b * SK_ + kv0 + 16 * n + c];
#pragma unroll
            for (int r = 0; r < 4; ++r) sv[n][r] = s[r] + mv;
        }

        // online softmax, defer-max (THR=8): cheap per-lane check; full
        // cross-lane max + rescale only when the running max actually grew.
        float pmax[4];
#pragma unroll
        for (int r = 0; r < 4; ++r)
            pmax[r] = fmaxf(fmaxf(sv[0][r], sv[1][r]), fmaxf(sv[2][r], sv[3][r]));
        int ok = 1;
#pragma unroll
        for (int r = 0; r < 4; ++r) ok &= (pmax[r] <= m_run[r] + 8.f);
        if (!__all(ok)) {
            float alpha[4];
#pragma unroll
            for (int r = 0; r < 4; ++r) {
                float m_ = pmax[r];
                m_ = fmaxf(m_, __shfl_xor(m_, 1));
                m_ = fmaxf(m_, __shfl_xor(m_, 2));
                m_ = fmaxf(m_, __shfl_xor(m_, 4));
                m_ = fmaxf(m_, __shfl_xor(m_, 8));
                float mn = fmaxf(m_run[r], m_);
                alpha[r] = exp2f((m_run[r] - mn) * L2E);
                m_run[r] = mn;
                ps[r] *= alpha[r];
            }
#pragma unroll
            for (int nn = 0; nn < 4; ++nn)
#pragma unroll
                for (int r = 0; r < 4; ++r) o[nn][r] *= alpha[r];
        }
        // P = exp(S - m); accumulate per-lane partial row-sum (cross-lane sum deferred to end)
#pragma unroll
        for (int n = 0; n < 4; ++n)
#pragma unroll
            for (int r = 0; r < 4; ++r) {
                float p = exp2f((sv[n][r] - m_run[r]) * L2E);
                sv[n][r] = p;
                ps[r] += p;
            }

        // P -> bf16 -> per-wave LDS (swizzled), then re-read as A-fragments
#pragma unroll
        for (int n = 0; n < 4; ++n)
#pragma unroll
            for (int r = 0; r < 4; ++r) {
                int row = 4 * g + r;
                *(ushort*)((char*)&Ps[w][0] + row * 128 +
                           (((16 * n + c) * 2) ^ ((row & 7) << 4))) = f2bf(sv[n][r]);
            }
        s16x8 pa[2];
#pragma unroll
        for (int kk = 0; kk < 2; ++kk)
            pa[kk] = *(const s16x8*)((const char*)&Ps[w][0] + c * 128 +
                                     ((kk * 64 + g * 16) ^ ((c & 7) << 4)));
#pragma unroll
        for (int nn = 0; nn < 4; ++nn) {
#pragma unroll
            for (int kk = 0; kk < 2; ++kk) {
                const s16x8 bv_ = *(const s16x8*)((const char*)Vs + (16 * nn + c) * 128 +
                                                  ((kk * 64 + g * 16) ^ ((c & 7) << 4)));
                o[nn] = __builtin_amdgcn_mfma_f32_16x16x32_bf16(pa[kk], bv_, o[nn], 0, 0, 0);
            }
        }
    }

    // final cross-lane row-sum of the deferred partials, then normalize
    float inv[4];
#pragma unroll
    for (int r = 0; r < 4; ++r) {
        float s_ = ps[r];
        s_ += __shfl_xor(s_, 1);
        s_ += __shfl_xor(s_, 2);
        s_ += __shfl_xor(s_, 4);
        s_ += __shfl_xor(s_, 8);
        inv[r] = 1.f / s_;
    }
#pragma unroll
    for (int nn = 0; nn < 4; ++nn)
#pragma unroll
        for (int r = 0; r < 4; ++r)
            out[(size_t)(b * SQ_ + q0 + w * 16 + 4 * g + r) * D_ + h * HD_ + 16 * nn + c] =
                o[nn][r] * inv[r];
}

extern "C" void kernel_launch(void* const* d_in, const int* in_sizes, int n_in,
                              void* d_out, int out_size, void* d_ws, size_t ws_size,
                              hipStream_t stream) {
    (void)in_sizes; (void)n_in; (void)out_size; (void)ws_size;
    const float* hidden  = (const float*)d_in[0];
    const float* context = (const float*)d_in[1];
    const float* amask   = (const float*)d_in[2];
    const float* Wq = (const float*)d_in[3];
    const float* bq = (const float*)d_in[4];
    const float* Wk = (const float*)d_in[5];
    const float* bk = (const float*)d_in[6];
    const float* Wv = (const float*)d_in[7];
    const float* bv = (const float*)d_in[8];
    float* out = (float*)d_out;

    char* ws = (char*)d_ws;
    ushort* hb  = (ushort*)(ws);              // 12.6 MB  hidden bf16 [8192][768]
    ushort* cb  = (ushort*)(ws + 12582912);   // 12.6 MB  context bf16
    ushort* wqt = (ushort*)(ws + 25165824);   // 1.18 MB  Wq^T bf16 [768][768]
    ushort* wkt = (ushort*)(ws + 26345472);
    ushort* wvt = (ushort*)(ws + 27525120);
    ushort* qb  = (ushort*)(ws + 28704768);   // 12.6 MB  Q bf16 [8192][768]
    ushort* kb  = (ushort*)(ws + 41287680);   // 12.6 MB  K bf16 [8192][768]
    ushort* vt  = (ushort*)(ws + 53870592);   // 12.6 MB  V^T bf16 [B][H][64][1024]
    // total 66,453,504 bytes

    int n4 = (B_ * SQ_ * D_) / 4;
    convX<<<2048, 256, 0, stream>>>((const float4*)hidden, hb, n4);
    convX<<<2048, 256, 0, stream>>>((const float4*)context, cb, n4);
    dim3 gw(24, 24);
    convWT<<<gw, 256, 0, stream>>>(Wq, wqt);
    convWT<<<gw, 256, 0, stream>>>(Wk, wkt);
    convWT<<<gw, 256, 0, stream>>>(Wv, wvt);
    gemm_qkv<<<dim3(64, 6, 3), 256, 0, stream>>>(hb, cb, wqt, wkt, wvt, bq, bk, bv, qb, kb, vt);
    attn<<<dim3(16, 12, 8), 256, 0, stream>>>(qb, kb, vt, amask, out);
}

// Round 4
// 237.235 us; speedup vs baseline: 1.1070x; 1.0035x over previous
//
#include <hip/hip_runtime.h>
#include <hip/hip_bf16.h>
#include <cstdint>

#define B_  8
#define SQ_ 1024
#define SK_ 1024
#define D_  768
#define H_  12
#define HD_ 64

typedef __attribute__((ext_vector_type(8))) short s16x8;
typedef __attribute__((ext_vector_type(4))) float f32x4;

__device__ __forceinline__ float bf2f(ushort u) {
    union { uint32_t i; float f; } v; v.i = ((uint32_t)u) << 16; return v.f;
}
__device__ __forceinline__ ushort f2bf(float f) {
    __hip_bfloat16 h = __float2bfloat16(f);
    union { __hip_bfloat16 h; ushort u; } v; v.h = h; return v.u;
}
__device__ __forceinline__ uint32_t pk32(float a, float b) {
    return (uint32_t)f2bf(a) | ((uint32_t)f2bf(b) << 16);
}

// ---------------- convert f32 -> bf16 (vectorized) ----------------
__global__ void convX(const float4* __restrict__ src, ushort* __restrict__ dst, int n4) {
    int i = blockIdx.x * blockDim.x + threadIdx.x;
    int stride = gridDim.x * blockDim.x;
    for (; i < n4; i += stride) {
        float4 v = src[i];
        ushort4 o = { f2bf(v.x), f2bf(v.y), f2bf(v.z), f2bf(v.w) };
        *reinterpret_cast<ushort4*>(dst + (size_t)i * 4) = o;
    }
}

// ---------------- convert + transpose W[k][n] f32 -> WT[n][k] bf16 ----------------
__global__ void convWT(const float* __restrict__ W, ushort* __restrict__ WT) {
    __shared__ float t[32][33];
    int k0 = blockIdx.x * 32, n0 = blockIdx.y * 32;
    int tx = threadIdx.x & 31, ty = threadIdx.x >> 5;  // 32 x 8
#pragma unroll
    for (int rr = 0; rr < 4; ++rr)
        t[ty + 8 * rr][tx] = W[(size_t)(k0 + ty + 8 * rr) * D_ + n0 + tx];
    __syncthreads();
#pragma unroll
    for (int rr = 0; rr < 4; ++rr)
        WT[(size_t)(n0 + ty + 8 * rr) * D_ + k0 + tx] = f2bf(t[tx][ty + 8 * rr]);
}

// ---------------- QKV GEMM: C = A(bf16)[M][K] * WT(bf16)[N][K]^T + bias ----------------
#define GL16(g, l)                                                                     \
    __builtin_amdgcn_global_load_lds((const __attribute__((address_space(1))) void*)(g), \
                                     (__attribute__((address_space(3))) void*)(l), 16, 0, 0)

__global__ __launch_bounds__(256) void gemm_qkv(
    const ushort* __restrict__ hb, const ushort* __restrict__ cb,
    const ushort* __restrict__ wqt, const ushort* __restrict__ wkt, const ushort* __restrict__ wvt,
    const float* __restrict__ bq, const float* __restrict__ bk, const float* __restrict__ bv,
    ushort* __restrict__ qout, ushort* __restrict__ kout, ushort* __restrict__ vtout)
{
    const int z = blockIdx.z;
    const ushort* A    = (z == 0) ? hb : cb;
    const ushort* Wt   = (z == 0) ? wqt : (z == 1) ? wkt : wvt;
    const float*  bias = (z == 0) ? bq  : (z == 1) ? bk  : bv;

    __shared__ ushort As[128 * 32];
    __shared__ ushort Bs[128 * 32];

    const int tid = threadIdx.x;
    const int w = tid >> 6, l = tid & 63;
    const int g = l >> 4, c = l & 15;
    const int wr = w >> 1, wc = w & 1;
    const int m0 = blockIdx.x * 128;
    const int n0 = blockIdx.y * 128;

    f32x4 acc[4][4];
#pragma unroll
    for (int mi = 0; mi < 4; ++mi)
#pragma unroll
        for (int ni = 0; ni < 4; ++ni) acc[mi][ni] = (f32x4){0.f, 0.f, 0.f, 0.f};

    for (int kt = 0; kt < D_ / 32; ++kt) {
        __syncthreads();
#pragma unroll
        for (int j = 0; j < 2; ++j) {
            int cc = (j * 4 + w) * 64 + l;     // chunk 0..511, 16B each
            int row = cc >> 2, c8 = cc & 3;    // tile row, 16B-chunk within row
            const ushort* ga = A  + (size_t)(m0 + row) * D_ + kt * 32 + c8 * 8;
            GL16(ga, (char*)As + (size_t)(j * 4 + w) * 1024);
            const ushort* gb = Wt + (size_t)(n0 + row) * D_ + kt * 32 + c8 * 8;
            GL16(gb, (char*)Bs + (size_t)(j * 4 + w) * 1024);
        }
        __syncthreads();

        s16x8 af[4], bfr[4];
#pragma unroll
        for (int mi = 0; mi < 4; ++mi)
            af[mi] = *(const s16x8*)&As[(wr * 64 + mi * 16 + c) * 32 + g * 8];
#pragma unroll
        for (int ni = 0; ni < 4; ++ni)
            bfr[ni] = *(const s16x8*)&Bs[(wc * 64 + ni * 16 + c) * 32 + g * 8];
#pragma unroll
        for (int mi = 0; mi < 4; ++mi)
#pragma unroll
            for (int ni = 0; ni < 4; ++ni)
                acc[mi][ni] = __builtin_amdgcn_mfma_f32_16x16x32_bf16(af[mi], bfr[ni], acc[mi][ni], 0, 0, 0);
    }

    if (z < 2) {
        ushort* Out = (z == 0) ? qout : kout;
#pragma unroll
        for (int ni = 0; ni < 4; ++ni) {
            int ncol = n0 + wc * 64 + ni * 16 + c;
            float bv_ = bias[ncol];
#pragma unroll
            for (int mi = 0; mi < 4; ++mi) {
#pragma unroll
                for (int r = 0; r < 4; ++r) {
                    int mrow = m0 + wr * 64 + mi * 16 + 4 * g + r;
                    Out[(size_t)mrow * D_ + ncol] = f2bf(acc[mi][ni][r] + bv_);
                }
            }
        }
    } else {
        // V: write transposed per-head: VT[((b*H + h)*HD + d)*SK + s]
#pragma unroll
        for (int ni = 0; ni < 4; ++ni) {
            int ncol = n0 + wc * 64 + ni * 16 + c;
            float bv_ = bias[ncol];
            int hh = ncol >> 6, dd = ncol & 63;
#pragma unroll
            for (int mi = 0; mi < 4; ++mi) {
                int mrow = m0 + wr * 64 + mi * 16 + 4 * g;   // 4 consecutive rows
                int bb = mrow >> 10, ss = mrow & 1023;
                ushort4 pk;
                pk.x = f2bf(acc[mi][ni][0] + bv_);
                pk.y = f2bf(acc[mi][ni][1] + bv_);
                pk.z = f2bf(acc[mi][ni][2] + bv_);
                pk.w = f2bf(acc[mi][ni][3] + bv_);
                *reinterpret_cast<ushort4*>(vtout + (size_t)((bb * H_ + hh) * HD_ + dd) * SK_ + ss) = pk;
            }
        }
    }
}

// ---------------- flash attention v2: swapped QK^T, in-register P repack,
// ---------------- double-buffered K/V with issue-early staging, 1 barrier/tile
__global__ __launch_bounds__(256) void attn(
    const ushort* __restrict__ Qb, const ushort* __restrict__ Kb, const ushort* __restrict__ VT,
    const float* __restrict__ amask, float* __restrict__ out)
{
    __shared__ ushort Ks[2][64 * 64];   // K tile [kv][d], XOR-swizzled rows (128 B)
    __shared__ ushort Vs[2][64 * 64];   // V^T tile [d][kv], XOR-swizzled rows
    __shared__ float  Ms[1024];         // whole mask row for this b

    const int tid = threadIdx.x;
    const int w = tid >> 6, l = tid & 63;
    const int g = l >> 4, c = l & 15;
    const int q0 = blockIdx.x * 64;
    const int h  = blockIdx.y;
    const int b  = blockIdx.z;
    const int xsw = (c & 7) << 4;                 // frag-read swizzle
    const int lane0 = c + 16 * ((2 * g) & 3);     // repack source lanes
    const int lane1 = c + 16 * ((2 * g + 1) & 3);
    const bool hi_ = (g >= 2);
    const float L2E = 1.44269504f;

    // mask row -> LDS (once)
#pragma unroll
    for (int i = 0; i < 4; ++i) Ms[tid + 256 * i] = amask[b * SK_ + tid + 256 * i];

    // Q fragment (B-operand: lane holds Q[q=c][d=8g+j]), pre-scaled by 0.125
    s16x8 qf[2];
#pragma unroll
    for (int kk = 0; kk < 2; ++kk) {
        const ushort* gq = Qb + (size_t)(b * SQ_ + q0 + w * 16 + c) * D_ + h * HD_ + kk * 32 + g * 8;
        s16x8 v = *(const s16x8*)gq;
#pragma unroll
        for (int i = 0; i < 8; ++i) v[i] = (short)f2bf(bf2f((ushort)v[i]) * 0.125f);
        qf[kk] = v;
    }

    // staging: thread covers chunks {tid, tid+256}: row0=tid>>3 and row0+32, c8=tid&7
    const int row0 = tid >> 3, c8 = tid & 7;
    const int ldsoff = row0 * 128 + ((c8 * 16) ^ ((row0 & 7) << 4));  // (row+32)&7 == row&7
    const ushort* kp = Kb + (size_t)(b * SK_ + row0) * D_ + h * HD_ + c8 * 8;
    const ushort* vp = VT + (size_t)((b * H_ + h) * HD_ + row0) * SK_ + c8 * 8;

    // prologue: stage tile 0 into buffer 0
    {
        uint4 k0 = *(const uint4*)kp, k1 = *(const uint4*)(kp + 32 * D_);
        uint4 v0 = *(const uint4*)vp, v1 = *(const uint4*)(vp + 32 * SK_);
        *(uint4*)((char*)Ks[0] + ldsoff) = k0;
        *(uint4*)((char*)Ks[0] + ldsoff + 4096) = k1;
        *(uint4*)((char*)Vs[0] + ldsoff) = v0;
        *(uint4*)((char*)Vs[0] + ldsoff + 4096) = v1;
        kp += 64 * D_; vp += 64;
    }
    __syncthreads();

    f32x4 o[4];
#pragma unroll
    for (int nn = 0; nn < 4; ++nn) o[nn] = (f32x4){0.f, 0.f, 0.f, 0.f};
    float m_run = -INFINITY, ps = 0.f;

#define TILE(CUR, NXT, T)                                                              \
    {                                                                                  \
        /* issue next-tile loads early (clamped to tile 15) */                         \
        uint4 nk0 = *(const uint4*)kp;                                                 \
        uint4 nk1 = *(const uint4*)(kp + 32 * D_);                                     \
        uint4 nv0 = *(const uint4*)vp;                                                 \
        uint4 nv1 = *(const uint4*)(vp + 32 * SK_);                                    \
        if ((T) < 14) { kp += 64 * D_; vp += 64; }                                     \
        /* S^T = K * Q^T: lane(g,c) reg r = S[q=c][kv=16n+4g+r] */                     \
        float sv[4][4];                                                                \
        _Pragma("unroll")                                                              \
        for (int n = 0; n < 4; ++n) {                                                  \
            f32x4 s = (f32x4){0.f, 0.f, 0.f, 0.f};                                     \
            _Pragma("unroll")                                                          \
            for (int kk = 0; kk < 2; ++kk) {                                           \
                const s16x8 kf = *(const s16x8*)((const char*)Ks[CUR] +                \
                    (16 * n + c) * 128 + ((kk * 64 + g * 16) ^ xsw));                  \
                s = __builtin_amdgcn_mfma_f32_16x16x32_bf16(kf, qf[kk], s, 0, 0, 0);   \
            }                                                                          \
            const f32x4 mk = *(const f32x4*)&Ms[(T) * 64 + n * 16 + g * 4];            \
            _Pragma("unroll")                                                          \
            for (int r = 0; r < 4; ++r) sv[n][r] = s[r] + mk[r];                       \
        }                                                                              \
        /* defer-max online softmax (scalar state, q=c) */                             \
        float pmax = sv[0][0];                                                         \
        _Pragma("unroll")                                                              \
        for (int n = 0; n < 4; ++n)                                                    \
            _Pragma("unroll")                                                          \
            for (int r = 0; r < 4; ++r) pmax = fmaxf(pmax, sv[n][r]);                  \
        if (__any(pmax > m_run + 8.f)) {                                               \
            float mf = fmaxf(pmax, __shfl_xor(pmax, 16));                              \
            mf = fmaxf(mf, __shfl_xor(mf, 32));                                        \
            float mn = fmaxf(m_run, mf);                                               \
            float alpha = exp2f((m_run - mn) * L2E);                                   \
            m_run = mn; ps *= alpha;                                                   \
            float ar0 = __shfl(alpha, 4 * g), ar1 = __shfl(alpha, 4 * g + 1);          \
            float ar2 = __shfl(alpha, 4 * g + 2), ar3 = __shfl(alpha, 4 * g + 3);      \
            _Pragma("unroll")                                                          \
            for (int nn = 0; nn < 4; ++nn) {                                           \
                o[nn][0] *= ar0; o[nn][1] *= ar1; o[nn][2] *= ar2; o[nn][3] *= ar3;    \
            }                                                                          \
        }                                                                              \
        /* P = exp(S-m), pack pairs to bf16 dwords */                                  \
        uint32_t pk[4][2];                                                             \
        _Pragma("unroll")                                                              \
        for (int n = 0; n < 4; ++n) {                                                  \
            float p0 = exp2f((sv[n][0] - m_run) * L2E);                                \
            float p1 = exp2f((sv[n][1] - m_run) * L2E);                                \
            float p2 = exp2f((sv[n][2] - m_run) * L2E);                                \
            float p3 = exp2f((sv[n][3] - m_run) * L2E);                                \
            ps += (p0 + p1) + (p2 + p3);                                               \
            pk[n][0] = pk32(p0, p1); pk[n][1] = pk32(p2, p3);                          \
        }                                                                              \
        /* repack C/D->A-frag: slot(kk,dw) <- pk[2kk+(g>>1)][dw&1] of lane(dw<2?lane0:lane1) */ \
        s16x8 pa0, pa1;                                                                \
        {                                                                              \
            union { uint32_t u[4]; s16x8 v; } ua, ub;                                  \
            uint32_t a0 = __shfl((int)pk[0][0], lane0), b0 = __shfl((int)pk[1][0], lane0); \
            uint32_t a1 = __shfl((int)pk[0][1], lane0), b1 = __shfl((int)pk[1][1], lane0); \
            uint32_t a2 = __shfl((int)pk[0][0], lane1), b2 = __shfl((int)pk[1][0], lane1); \
            uint32_t a3 = __shfl((int)pk[0][1], lane1), b3 = __shfl((int)pk[1][1], lane1); \
            ua.u[0] = hi_ ? b0 : a0; ua.u[1] = hi_ ? b1 : a1;                          \
            ua.u[2] = hi_ ? b2 : a2; ua.u[3] = hi_ ? b3 : a3;                          \
            uint32_t c0 = __shfl((int)pk[2][0], lane0), d0 = __shfl((int)pk[3][0], lane0); \
            uint32_t c1 = __shfl((int)pk[2][1], lane0), d1 = __shfl((int)pk[3][1], lane0); \
            uint32_t c2 = __shfl((int)pk[2][0], lane1), d2 = __shfl((int)pk[3][0], lane1); \
            uint32_t c3 = __shfl((int)pk[2][1], lane1), d3 = __shfl((int)pk[3][1], lane1); \
            ub.u[0] = hi_ ? d0 : c0; ub.u[1] = hi_ ? d1 : c1;                          \
            ub.u[2] = hi_ ? d2 : c2; ub.u[3] = hi_ ? d3 : c3;                          \
            pa0 = ua.v; pa1 = ub.v;                                                    \
        }                                                                              \
        /* O += P * V */                                                               \
        _Pragma("unroll")                                                              \
        for (int nn = 0; nn < 4; ++nn) {                                               \
            const s16x8 vf0 = *(const s16x8*)((const char*)Vs[CUR] +                   \
                (16 * nn + c) * 128 + ((g * 16) ^ xsw));                               \
            o[nn] = __builtin_amdgcn_mfma_f32_16x16x32_bf16(pa0, vf0, o[nn], 0, 0, 0); \
            const s16x8 vf1 = *(const s16x8*)((const char*)Vs[CUR] +                   \
                (16 * nn + c) * 128 + ((64 + g * 16) ^ xsw));                          \
            o[nn] = __builtin_amdgcn_mfma_f32_16x16x32_bf16(pa1, vf1, o[nn], 0, 0, 0); \
        }                                                                              \
        /* write staged regs -> other buffer; single barrier per tile */               \
        *(uint4*)((char*)Ks[NXT] + ldsoff) = nk0;                                      \
        *(uint4*)((char*)Ks[NXT] + ldsoff + 4096) = nk1;                               \
        *(uint4*)((char*)Vs[NXT] + ldsoff) = nv0;                                      \
        *(uint4*)((char*)Vs[NXT] + ldsoff + 4096) = nv1;                               \
        __syncthreads();                                                               \
    }

    for (int tt = 0; tt < 8; ++tt) {
        TILE(0, 1, 2 * tt)
        TILE(1, 0, 2 * tt + 1)
    }
#undef TILE

    // finish: full row-sum (q=c), redistribute 1/sum to q=4g+r rows, write out
    ps += __shfl_xor(ps, 16);
    ps += __shfl_xor(ps, 32);
    float invc = 1.f / ps;
    float ir0 = __shfl(invc, 4 * g), ir1 = __shfl(invc, 4 * g + 1);
    float ir2 = __shfl(invc, 4 * g + 2), ir3 = __shfl(invc, 4 * g + 3);
#pragma unroll
    for (int nn = 0; nn < 4; ++nn) {
        float* op = out + (size_t)(b * SQ_ + q0 + w * 16 + 4 * g) * D_ + h * HD_ + 16 * nn + c;
        op[0]      = o[nn][0] * ir0;
        op[D_]     = o[nn][1] * ir1;
        op[2 * D_] = o[nn][2] * ir2;
        op[3 * D_] = o[nn][3] * ir3;
    }
}

extern "C" void kernel_launch(void* const* d_in, const int* in_sizes, int n_in,
                              void* d_out, int out_size, void* d_ws, size_t ws_size,
                              hipStream_t stream) {
    (void)in_sizes; (void)n_in; (void)out_size; (void)ws_size;
    const float* hidden  = (const float*)d_in[0];
    const float* context = (const float*)d_in[1];
    const float* amask   = (const float*)d_in[2];
    const float* Wq = (const float*)d_in[3];
    const float* bq = (const float*)d_in[4];
    const float* Wk = (const float*)d_in[5];
    const float* bk = (const float*)d_in[6];
    const float* Wv = (const float*)d_in[7];
    const float* bv = (const float*)d_in[8];
    float* out = (float*)d_out;

    char* ws = (char*)d_ws;
    ushort* hb  = (ushort*)(ws);              // 12.6 MB  hidden bf16 [8192][768]
    ushort* cb  = (ushort*)(ws + 12582912);   // 12.6 MB  context bf16
    ushort* wqt = (ushort*)(ws + 25165824);   // 1.18 MB  Wq^T bf16 [768][768]
    ushort* wkt = (ushort*)(ws + 26345472);
    ushort* wvt = (ushort*)(ws + 27525120);
    ushort* qb  = (ushort*)(ws + 28704768);   // 12.6 MB  Q bf16 [8192][768]
    ushort* kb  = (ushort*)(ws + 41287680);   // 12.6 MB  K bf16 [8192][768]
    ushort* vt  = (ushort*)(ws + 53870592);   // 12.6 MB  V^T bf16 [B][H][64][1024]
    // total 66,453,504 bytes

    int n4 = (B_ * SQ_ * D_) / 4;
    convX<<<2048, 256, 0, stream>>>((const float4*)hidden, hb, n4);
    convX<<<2048, 256, 0, stream>>>((const float4*)context, cb, n4);
    dim3 gw(24, 24);
    convWT<<<gw, 256, 0, stream>>>(Wq, wqt);
    convWT<<<gw, 256, 0, stream>>>(Wk, wkt);
    convWT<<<gw, 256, 0, stream>>>(Wv, wvt);
    gemm_qkv<<<dim3(64, 6, 3), 256, 0, stream>>>(hb, cb, wqt, wkt, wvt, bq, bk, bv, qb, kb, vt);
    attn<<<dim3(16, 12, 8), 256, 0, stream>>>(qb, kb, vt, amask, out);
}

// Round 5
// 234.683 us; speedup vs baseline: 1.1190x; 1.0109x over previous
//
#include <hip/hip_runtime.h>
#include <hip/hip_bf16.h>
#include <cstdint>

#define B_  8
#define SQ_ 1024
#define SK_ 1024
#define D_  768
#define H_  12
#define HD_ 64

typedef __attribute__((ext_vector_type(8))) short s16x8;
typedef __attribute__((ext_vector_type(4))) float f32x4;
typedef __attribute__((ext_vector_type(16))) float f32x16;

__device__ __forceinline__ float bf2f(ushort u) {
    union { uint32_t i; float f; } v; v.i = ((uint32_t)u) << 16; return v.f;
}
__device__ __forceinline__ ushort f2bf(float f) {
    __hip_bfloat16 h = __float2bfloat16(f);
    union { __hip_bfloat16 h; ushort u; } v; v.h = h; return v.u;
}
__device__ __forceinline__ uint32_t pk32(float a, float b) {
    return (uint32_t)f2bf(a) | ((uint32_t)f2bf(b) << 16);
}
__device__ __forceinline__ float fexp2(float x) {
#if __has_builtin(__builtin_amdgcn_exp2f)
    return __builtin_amdgcn_exp2f(x);
#else
    return exp2f(x);
#endif
}
// exchange across lane+-32: x = [a_lo, b_lo], y = [a_hi, b_hi]
__device__ __forceinline__ void xch(uint32_t a, uint32_t b, bool lo, uint32_t& x, uint32_t& y) {
    uint32_t bx = (uint32_t)__shfl_xor((int)b, 32);
    uint32_t ax = (uint32_t)__shfl_xor((int)a, 32);
    x = lo ? a : bx;
    y = lo ? ax : b;
}

// ---------------- convert f32 -> bf16 (vectorized) ----------------
__global__ void convX(const float4* __restrict__ src, ushort* __restrict__ dst, int n4) {
    int i = blockIdx.x * blockDim.x + threadIdx.x;
    int stride = gridDim.x * blockDim.x;
    for (; i < n4; i += stride) {
        float4 v = src[i];
        ushort4 o = { f2bf(v.x), f2bf(v.y), f2bf(v.z), f2bf(v.w) };
        *reinterpret_cast<ushort4*>(dst + (size_t)i * 4) = o;
    }
}

// ---------------- convert + transpose W[k][n] f32 -> WT[n][k] bf16 ----------------
__global__ void convWT(const float* __restrict__ W, ushort* __restrict__ WT) {
    __shared__ float t[32][33];
    int k0 = blockIdx.x * 32, n0 = blockIdx.y * 32;
    int tx = threadIdx.x & 31, ty = threadIdx.x >> 5;  // 32 x 8
#pragma unroll
    for (int rr = 0; rr < 4; ++rr)
        t[ty + 8 * rr][tx] = W[(size_t)(k0 + ty + 8 * rr) * D_ + n0 + tx];
    __syncthreads();
#pragma unroll
    for (int rr = 0; rr < 4; ++rr)
        WT[(size_t)(n0 + ty + 8 * rr) * D_ + k0 + tx] = f2bf(t[tx][ty + 8 * rr]);
}

// ---------------- QKV GEMM: C = A(bf16)[M][K] * WT(bf16)[N][K]^T + bias ----------------
#define GL16(g, l)                                                                     \
    __builtin_amdgcn_global_load_lds((const __attribute__((address_space(1))) void*)(g), \
                                     (__attribute__((address_space(3))) void*)(l), 16, 0, 0)

__global__ __launch_bounds__(256) void gemm_qkv(
    const ushort* __restrict__ hb, const ushort* __restrict__ cb,
    const ushort* __restrict__ wqt, const ushort* __restrict__ wkt, const ushort* __restrict__ wvt,
    const float* __restrict__ bq, const float* __restrict__ bk, const float* __restrict__ bv,
    ushort* __restrict__ qout, ushort* __restrict__ kout, ushort* __restrict__ vtout)
{
    const int z = blockIdx.z;
    const ushort* A    = (z == 0) ? hb : cb;
    const ushort* Wt   = (z == 0) ? wqt : (z == 1) ? wkt : wvt;
    const float*  bias = (z == 0) ? bq  : (z == 1) ? bk  : bv;

    __shared__ ushort As[128 * 32];
    __shared__ ushort Bs[128 * 32];

    const int tid = threadIdx.x;
    const int w = tid >> 6, l = tid & 63;
    const int g = l >> 4, c = l & 15;
    const int wr = w >> 1, wc = w & 1;
    const int m0 = blockIdx.x * 128;
    const int n0 = blockIdx.y * 128;

    f32x4 acc[4][4];
#pragma unroll
    for (int mi = 0; mi < 4; ++mi)
#pragma unroll
        for (int ni = 0; ni < 4; ++ni) acc[mi][ni] = (f32x4){0.f, 0.f, 0.f, 0.f};

    for (int kt = 0; kt < D_ / 32; ++kt) {
        __syncthreads();
#pragma unroll
        for (int j = 0; j < 2; ++j) {
            int cc = (j * 4 + w) * 64 + l;     // chunk 0..511, 16B each
            int row = cc >> 2, c8 = cc & 3;    // tile row, 16B-chunk within row
            const ushort* ga = A  + (size_t)(m0 + row) * D_ + kt * 32 + c8 * 8;
            GL16(ga, (char*)As + (size_t)(j * 4 + w) * 1024);
            const ushort* gb = Wt + (size_t)(n0 + row) * D_ + kt * 32 + c8 * 8;
            GL16(gb, (char*)Bs + (size_t)(j * 4 + w) * 1024);
        }
        __syncthreads();

        s16x8 af[4], bfr[4];
#pragma unroll
        for (int mi = 0; mi < 4; ++mi)
            af[mi] = *(const s16x8*)&As[(wr * 64 + mi * 16 + c) * 32 + g * 8];
#pragma unroll
        for (int ni = 0; ni < 4; ++ni)
            bfr[ni] = *(const s16x8*)&Bs[(wc * 64 + ni * 16 + c) * 32 + g * 8];
#pragma unroll
        for (int mi = 0; mi < 4; ++mi)
#pragma unroll
            for (int ni = 0; ni < 4; ++ni)
                acc[mi][ni] = __builtin_amdgcn_mfma_f32_16x16x32_bf16(af[mi], bfr[ni], acc[mi][ni], 0, 0, 0);
    }

    if (z < 2) {
        ushort* Out = (z == 0) ? qout : kout;
#pragma unroll
        for (int ni = 0; ni < 4; ++ni) {
            int ncol = n0 + wc * 64 + ni * 16 + c;
            float bv_ = bias[ncol];
#pragma unroll
            for (int mi = 0; mi < 4; ++mi) {
#pragma unroll
                for (int r = 0; r < 4; ++r) {
                    int mrow = m0 + wr * 64 + mi * 16 + 4 * g + r;
                    Out[(size_t)mrow * D_ + ncol] = f2bf(acc[mi][ni][r] + bv_);
                }
            }
        }
    } else {
        // V: write transposed per-head: VT[((b*H + h)*HD + d)*SK + s]
#pragma unroll
        for (int ni = 0; ni < 4; ++ni) {
            int ncol = n0 + wc * 64 + ni * 16 + c;
            float bv_ = bias[ncol];
            int hh = ncol >> 6, dd = ncol & 63;
#pragma unroll
            for (int mi = 0; mi < 4; ++mi) {
                int mrow = m0 + wr * 64 + mi * 16 + 4 * g;   // 4 consecutive rows
                int bb = mrow >> 10, ss = mrow & 1023;
                ushort4 pk;
                pk.x = f2bf(acc[mi][ni][0] + bv_);
                pk.y = f2bf(acc[mi][ni][1] + bv_);
                pk.z = f2bf(acc[mi][ni][2] + bv_);
                pk.w = f2bf(acc[mi][ni][3] + bv_);
                *reinterpret_cast<ushort4*>(vtout + (size_t)((bb * H_ + hh) * HD_ + dd) * SK_ + ss) = pk;
            }
        }
    }
}

// ---------------- flash attention v3: 32x32 MFMA, 64 q-rows/wave, in-lane softmax ----
#define MFMA32(a, b, c) __builtin_amdgcn_mfma_f32_32x32x16_bf16(a, b, c, 0, 0, 0)

// one q-subtile: softmax on S^T regs, repack to A-frags, PV into o0/o1
__device__ __forceinline__ void proc_qs(f32x16 sa, float& m_run, float& ps,
                                        f32x16& o0, f32x16& o1,
                                        const s16x8 v0a, const s16x8 v1a,
                                        const s16x8 v0b, const s16x8 v1b,
                                        const int hi, const bool lo)
{
    const float L2E = 1.44269504f;
    float a0 = fmaxf(fmaxf(sa[0], sa[1]), fmaxf(sa[2], sa[3]));
    float a1 = fmaxf(fmaxf(sa[4], sa[5]), fmaxf(sa[6], sa[7]));
    float a2 = fmaxf(fmaxf(sa[8], sa[9]), fmaxf(sa[10], sa[11]));
    float a3 = fmaxf(fmaxf(sa[12], sa[13]), fmaxf(sa[14], sa[15]));
    float pmax = fmaxf(fmaxf(a0, a1), fmaxf(a2, a3));
    if (__any(pmax > m_run + 8.f)) {            // rare: first tile + real max growth
        float mf = fmaxf(pmax, __shfl_xor(pmax, 32));
        float mn = fmaxf(m_run, mf);
        float alpha = fexp2((m_run - mn) * L2E);
        m_run = mn; ps *= alpha;
#pragma unroll
        for (int r = 0; r < 16; ++r) {
            float ar = __shfl(alpha, (r & 3) + 8 * (r >> 2) + 4 * hi);
            o0[r] *= ar; o1[r] *= ar;
        }
    }
    float ml = m_run * L2E;
    float p[16];
#pragma unroll
    for (int r = 0; r < 16; ++r) p[r] = fexp2(sa[r] * L2E - ml);
    ps += (((p[0] + p[1]) + (p[2] + p[3])) + ((p[4] + p[5]) + (p[6] + p[7]))) +
          (((p[8] + p[9]) + (p[10] + p[11])) + ((p[12] + p[13]) + (p[14] + p[15])));
    uint32_t cc[8];
#pragma unroll
    for (int j = 0; j < 8; ++j) cc[j] = pk32(p[2 * j], p[2 * j + 1]);
    uint32_t d0, d1, d2, d3, e0, e1, e2, e3;
    xch(cc[0], cc[2], lo, d0, d2);
    xch(cc[1], cc[3], lo, d1, d3);
    xch(cc[4], cc[6], lo, e0, e2);
    xch(cc[5], cc[7], lo, e1, e3);
    union { uint32_t u[4]; s16x8 v; } ua, ub;
    ua.u[0] = d0; ua.u[1] = d1; ua.u[2] = d2; ua.u[3] = d3;
    ub.u[0] = e0; ub.u[1] = e1; ub.u[2] = e2; ub.u[3] = e3;
    o0 = MFMA32(ua.v, v0a, o0);
    o0 = MFMA32(ub.v, v1a, o0);
    o1 = MFMA32(ua.v, v0b, o1);
    o1 = MFMA32(ub.v, v1b, o1);
}

__global__ __launch_bounds__(128, 2) void attn(
    const ushort* __restrict__ Qb, const ushort* __restrict__ Kb, const ushort* __restrict__ VT,
    const float* __restrict__ amask, float* __restrict__ out)
{
    __shared__ ushort Ks[2][64 * 64];   // K tile [kv][d], XOR-swizzled 128B rows
    __shared__ ushort Vs[2][64 * 64];   // V^T tile [d][kv], XOR-swizzled
    __shared__ float  Ms[1024];         // mask row for this b

    const int tid = threadIdx.x;
    const int w   = tid >> 6;           // wave 0..1
    const int l   = tid & 63;
    const int hi  = l >> 5;
    const int l31 = l & 31;
    const bool lo = (hi == 0);
    const int swz = (l31 & 7) << 4;
    const int q0  = blockIdx.x * 128 + w * 64;
    const int h = blockIdx.y, b = blockIdx.z;

    ((float4*)Ms)[tid]       = ((const float4*)(amask + b * SK_))[tid];
    ((float4*)Ms)[tid + 128] = ((const float4*)(amask + b * SK_))[tid + 128];

    // Q B-frags (2 q-subtiles x 4 k-slices), pre-scaled by 1/8
    s16x8 qf[2][4];
#pragma unroll
    for (int qs = 0; qs < 2; ++qs)
#pragma unroll
        for (int s = 0; s < 4; ++s) {
            const ushort* gq = Qb + (size_t)(b * SQ_ + q0 + qs * 32 + l31) * D_ + h * HD_ + s * 16 + hi * 8;
            s16x8 v = *(const s16x8*)gq;
#pragma unroll
            for (int i = 0; i < 8; ++i) v[i] = (short)f2bf(bf2f((ushort)v[i]) * 0.125f);
            qf[qs][s] = v;
        }

    // staging: thread -> (row0 = tid>>3) + 16*i rows, 16B chunk c8 = tid&7
    const int row0 = tid >> 3, c8 = tid & 7;
    const int ldsoff = row0 * 128 + ((c8 * 16) ^ ((row0 & 7) << 4));
    const ushort* kp = Kb + (size_t)(b * SK_ + row0) * D_ + h * HD_ + c8 * 8;
    const ushort* vp = VT + (size_t)((b * H_ + h) * HD_ + row0) * SK_ + c8 * 8;

    // prologue: tile 0 -> buffer 0
    {
#pragma unroll
        for (int i = 0; i < 4; ++i) {
            *(uint4*)((char*)Ks[0] + ldsoff + 2048 * i) = *(const uint4*)(kp + i * 16 * D_);
            *(uint4*)((char*)Vs[0] + ldsoff + 2048 * i) = *(const uint4*)(vp + i * 16 * SK_);
        }
        kp += 64 * D_; vp += 64;
    }
    __syncthreads();

    f32x16 o[2][2];
#pragma unroll
    for (int qs = 0; qs < 2; ++qs)
#pragma unroll
        for (int db = 0; db < 2; ++db)
#pragma unroll
            for (int r = 0; r < 16; ++r) o[qs][db][r] = 0.f;
    float m_run[2] = { -INFINITY, -INFINITY };
    float ps[2] = { 0.f, 0.f };

#define TILE(CUR, NXT, T)                                                              \
    {                                                                                  \
        uint4 nk0 = *(const uint4*)(kp);                                               \
        uint4 nk1 = *(const uint4*)(kp + 16 * D_);                                     \
        uint4 nk2 = *(const uint4*)(kp + 32 * D_);                                     \
        uint4 nk3 = *(const uint4*)(kp + 48 * D_);                                     \
        uint4 nv0 = *(const uint4*)(vp);                                               \
        uint4 nv1 = *(const uint4*)(vp + 16 * SK_);                                    \
        uint4 nv2 = *(const uint4*)(vp + 32 * SK_);                                    \
        uint4 nv3 = *(const uint4*)(vp + 48 * SK_);                                    \
        if ((T) < 14) { kp += 64 * D_; vp += 64; }                                     \
        _Pragma("unroll")                                                              \
        for (int blk = 0; blk < 2; ++blk) {                                            \
            const int kvb = (T) * 64 + blk * 32;                                       \
            union { f32x4 q[4]; f32x16 v; } mku;                                       \
            _Pragma("unroll")                                                          \
            for (int t = 0; t < 4; ++t)                                                \
                mku.q[t] = *(const f32x4*)&Ms[kvb + 4 * hi + 8 * t];                   \
            s16x8 kfr[4];                                                              \
            _Pragma("unroll")                                                          \
            for (int s = 0; s < 4; ++s)                                                \
                kfr[s] = *(const s16x8*)((const char*)Ks[CUR] + (blk * 32 + l31) * 128 \
                                         + ((s * 32 + hi * 16) ^ swz));                \
            s16x8 vfr[2][2];                                                           \
            _Pragma("unroll")                                                          \
            for (int sl = 0; sl < 2; ++sl)                                             \
                _Pragma("unroll")                                                      \
                for (int db = 0; db < 2; ++db)                                         \
                    vfr[sl][db] = *(const s16x8*)((const char*)Vs[CUR] +               \
                        (db * 32 + l31) * 128 + ((blk * 64 + sl * 32 + hi * 16) ^ swz)); \
            _Pragma("unroll")                                                          \
            for (int qs = 0; qs < 2; ++qs) {                                           \
                f32x16 sa = MFMA32(kfr[0], qf[qs][0], mku.v);                          \
                sa = MFMA32(kfr[1], qf[qs][1], sa);                                    \
                sa = MFMA32(kfr[2], qf[qs][2], sa);                                    \
                sa = MFMA32(kfr[3], qf[qs][3], sa);                                    \
                proc_qs(sa, m_run[qs], ps[qs], o[qs][0], o[qs][1],                     \
                        vfr[0][0], vfr[1][0], vfr[0][1], vfr[1][1], hi, lo);           \
            }                                                                          \
        }                                                                              \
        *(uint4*)((char*)Ks[NXT] + ldsoff)        = nk0;                               \
        *(uint4*)((char*)Ks[NXT] + ldsoff + 2048) = nk1;                               \
        *(uint4*)((char*)Ks[NXT] + ldsoff + 4096) = nk2;                               \
        *(uint4*)((char*)Ks[NXT] + ldsoff + 6144) = nk3;                               \
        *(uint4*)((char*)Vs[NXT] + ldsoff)        = nv0;                               \
        *(uint4*)((char*)Vs[NXT] + ldsoff + 2048) = nv1;                               \
        *(uint4*)((char*)Vs[NXT] + ldsoff + 4096) = nv2;                               \
        *(uint4*)((char*)Vs[NXT] + ldsoff + 6144) = nv3;                               \
        __syncthreads();                                                               \
    }

    for (int tt = 0; tt < 8; ++tt) {
        TILE(0, 1, 2 * tt)
        TILE(1, 0, 2 * tt + 1)
    }
#undef TILE

    // epilogue: row-sum across hi halves, normalize, write f32
#pragma unroll
    for (int qs = 0; qs < 2; ++qs) {
        float pf = ps[qs] + __shfl_xor(ps[qs], 32);
        float inv = 1.f / pf;
#pragma unroll
        for (int r = 0; r < 16; ++r) {
            int qr = (r & 3) + 8 * (r >> 2) + 4 * hi;
            float iv = __shfl(inv, qr);
            float* op = out + (size_t)(b * SQ_ + q0 + qs * 32 + qr) * D_ + h * HD_ + l31;
            op[0]  = o[qs][0][r] * iv;
            op[32] = o[qs][1][r] * iv;
        }
    }
}

extern "C" void kernel_launch(void* const* d_in, const int* in_sizes, int n_in,
                              void* d_out, int out_size, void* d_ws, size_t ws_size,
                              hipStream_t stream) {
    (void)in_sizes; (void)n_in; (void)out_size; (void)ws_size;
    const float* hidden  = (const float*)d_in[0];
    const float* context = (const float*)d_in[1];
    const float* amask   = (const float*)d_in[2];
    const float* Wq = (const float*)d_in[3];
    const float* bq = (const float*)d_in[4];
    const float* Wk = (const float*)d_in[5];
    const float* bk = (const float*)d_in[6];
    const float* Wv = (const float*)d_in[7];
    const float* bv = (const float*)d_in[8];
    float* out = (float*)d_out;

    char* ws = (char*)d_ws;
    ushort* hb  = (ushort*)(ws);              // 12.6 MB  hidden bf16 [8192][768]
    ushort* cb  = (ushort*)(ws + 12582912);   // 12.6 MB  context bf16
    ushort* wqt = (ushort*)(ws + 25165824);   // 1.18 MB  Wq^T bf16 [768][768]
    ushort* wkt = (ushort*)(ws + 26345472);
    ushort* wvt = (ushort*)(ws + 27525120);
    ushort* qb  = (ushort*)(ws + 28704768);   // 12.6 MB  Q bf16 [8192][768]
    ushort* kb  = (ushort*)(ws + 41287680);   // 12.6 MB  K bf16 [8192][768]
    ushort* vt  = (ushort*)(ws + 53870592);   // 12.6 MB  V^T bf16 [B][H][64][1024]
    // total 66,453,504 bytes

    int n4 = (B_ * SQ_ * D_) / 4;
    convX<<<2048, 256, 0, stream>>>((const float4*)hidden, hb, n4);
    convX<<<2048, 256, 0, stream>>>((const float4*)context, cb, n4);
    dim3 gw(24, 24);
    convWT<<<gw, 256, 0, stream>>>(Wq, wqt);
    convWT<<<gw, 256, 0, stream>>>(Wk, wkt);
    convWT<<<gw, 256, 0, stream>>>(Wv, wvt);
    gemm_qkv<<<dim3(64, 6, 3), 256, 0, stream>>>(hb, cb, wqt, wkt, wvt, bq, bk, bv, qb, kb, vt);
    attn<<<dim3(8, 12, 8), 128, 0, stream>>>(qb, kb, vt, amask, out);
}

// Round 6
// 218.650 us; speedup vs baseline: 1.2010x; 1.0733x over previous
//
#include <hip/hip_runtime.h>
#include <hip/hip_bf16.h>
#include <cstdint>

#define B_  8
#define SQ_ 1024
#define SK_ 1024
#define D_  768
#define H_  12
#define HD_ 64

typedef __attribute__((ext_vector_type(8))) short s16x8;
typedef __attribute__((ext_vector_type(4))) float f32x4;
typedef __attribute__((ext_vector_type(16))) float f32x16;

__device__ __forceinline__ float bf2f(ushort u) {
    union { uint32_t i; float f; } v; v.i = ((uint32_t)u) << 16; return v.f;
}
__device__ __forceinline__ ushort f2bf(float f) {
    __hip_bfloat16 h = __float2bfloat16(f);
    union { __hip_bfloat16 h; ushort u; } v; v.h = h; return v.u;
}
__device__ __forceinline__ uint32_t pk32(float a, float b) {
    return (uint32_t)f2bf(a) | ((uint32_t)f2bf(b) << 16);
}
__device__ __forceinline__ float fexp2(float x) {
#if __has_builtin(__builtin_amdgcn_exp2f)
    return __builtin_amdgcn_exp2f(x);
#else
    return exp2f(x);
#endif
}
// exchange across lane+-32: x = [a_lo, b_lo], y = [a_hi, b_hi]
__device__ __forceinline__ void xch(uint32_t a, uint32_t b, bool lo, uint32_t& x, uint32_t& y) {
    uint32_t bx = (uint32_t)__shfl_xor((int)b, 32);
    uint32_t ax = (uint32_t)__shfl_xor((int)a, 32);
    x = lo ? a : bx;
    y = lo ? ax : b;
}

// ---------------- convert f32 -> bf16 (vectorized) ----------------
__global__ void convX(const float4* __restrict__ src, ushort* __restrict__ dst, int n4) {
    int i = blockIdx.x * blockDim.x + threadIdx.x;
    int stride = gridDim.x * blockDim.x;
    for (; i < n4; i += stride) {
        float4 v = src[i];
        ushort4 o = { f2bf(v.x), f2bf(v.y), f2bf(v.z), f2bf(v.w) };
        *reinterpret_cast<ushort4*>(dst + (size_t)i * 4) = o;
    }
}

// ---------------- convert + transpose W[k][n] f32 -> WT[n][k] bf16 ----------------
__global__ void convWT(const float* __restrict__ W, ushort* __restrict__ WT) {
    __shared__ float t[32][33];
    int k0 = blockIdx.x * 32, n0 = blockIdx.y * 32;
    int tx = threadIdx.x & 31, ty = threadIdx.x >> 5;  // 32 x 8
#pragma unroll
    for (int rr = 0; rr < 4; ++rr)
        t[ty + 8 * rr][tx] = W[(size_t)(k0 + ty + 8 * rr) * D_ + n0 + tx];
    __syncthreads();
#pragma unroll
    for (int rr = 0; rr < 4; ++rr)
        WT[(size_t)(n0 + ty + 8 * rr) * D_ + k0 + tx] = f2bf(t[tx][ty + 8 * rr]);
}

// ---------------- QKV GEMM: C = A(bf16)[M][K] * WT(bf16)[N][K]^T + bias ----------------
#define GL16(g, l)                                                                     \
    __builtin_amdgcn_global_load_lds((const __attribute__((address_space(1))) void*)(g), \
                                     (__attribute__((address_space(3))) void*)(l), 16, 0, 0)

__global__ __launch_bounds__(256) void gemm_qkv(
    const ushort* __restrict__ hb, const ushort* __restrict__ cb,
    const ushort* __restrict__ wqt, const ushort* __restrict__ wkt, const ushort* __restrict__ wvt,
    const float* __restrict__ bq, const float* __restrict__ bk, const float* __restrict__ bv,
    ushort* __restrict__ qout, ushort* __restrict__ kout, ushort* __restrict__ vtout)
{
    const int z = blockIdx.z;
    const ushort* A    = (z == 0) ? hb : cb;
    const ushort* Wt   = (z == 0) ? wqt : (z == 1) ? wkt : wvt;
    const float*  bias = (z == 0) ? bq  : (z == 1) ? bk  : bv;

    __shared__ ushort As[128 * 32];
    __shared__ ushort Bs[128 * 32];

    const int tid = threadIdx.x;
    const int w = tid >> 6, l = tid & 63;
    const int g = l >> 4, c = l & 15;
    const int wr = w >> 1, wc = w & 1;
    const int m0 = blockIdx.x * 128;
    const int n0 = blockIdx.y * 128;

    f32x4 acc[4][4];
#pragma unroll
    for (int mi = 0; mi < 4; ++mi)
#pragma unroll
        for (int ni = 0; ni < 4; ++ni) acc[mi][ni] = (f32x4){0.f, 0.f, 0.f, 0.f};

    for (int kt = 0; kt < D_ / 32; ++kt) {
        __syncthreads();
#pragma unroll
        for (int j = 0; j < 2; ++j) {
            int cc = (j * 4 + w) * 64 + l;     // chunk 0..511, 16B each
            int row = cc >> 2, c8 = cc & 3;    // tile row, 16B-chunk within row
            const ushort* ga = A  + (size_t)(m0 + row) * D_ + kt * 32 + c8 * 8;
            GL16(ga, (char*)As + (size_t)(j * 4 + w) * 1024);
            const ushort* gb = Wt + (size_t)(n0 + row) * D_ + kt * 32 + c8 * 8;
            GL16(gb, (char*)Bs + (size_t)(j * 4 + w) * 1024);
        }
        __syncthreads();

        s16x8 af[4], bfr[4];
#pragma unroll
        for (int mi = 0; mi < 4; ++mi)
            af[mi] = *(const s16x8*)&As[(wr * 64 + mi * 16 + c) * 32 + g * 8];
#pragma unroll
        for (int ni = 0; ni < 4; ++ni)
            bfr[ni] = *(const s16x8*)&Bs[(wc * 64 + ni * 16 + c) * 32 + g * 8];
#pragma unroll
        for (int mi = 0; mi < 4; ++mi)
#pragma unroll
            for (int ni = 0; ni < 4; ++ni)
                acc[mi][ni] = __builtin_amdgcn_mfma_f32_16x16x32_bf16(af[mi], bfr[ni], acc[mi][ni], 0, 0, 0);
    }

    if (z < 2) {
        ushort* Out = (z == 0) ? qout : kout;
#pragma unroll
        for (int ni = 0; ni < 4; ++ni) {
            int ncol = n0 + wc * 64 + ni * 16 + c;
            float bv_ = bias[ncol];
#pragma unroll
            for (int mi = 0; mi < 4; ++mi) {
#pragma unroll
                for (int r = 0; r < 4; ++r) {
                    int mrow = m0 + wr * 64 + mi * 16 + 4 * g + r;
                    Out[(size_t)mrow * D_ + ncol] = f2bf(acc[mi][ni][r] + bv_);
                }
            }
        }
    } else {
        // V: write transposed per-head: VT[((b*H + h)*HD + d)*SK + s]
#pragma unroll
        for (int ni = 0; ni < 4; ++ni) {
            int ncol = n0 + wc * 64 + ni * 16 + c;
            float bv_ = bias[ncol];
            int hh = ncol >> 6, dd = ncol & 63;
#pragma unroll
            for (int mi = 0; mi < 4; ++mi) {
                int mrow = m0 + wr * 64 + mi * 16 + 4 * g;   // 4 consecutive rows
                int bb = mrow >> 10, ss = mrow & 1023;
                ushort4 pk;
                pk.x = f2bf(acc[mi][ni][0] + bv_);
                pk.y = f2bf(acc[mi][ni][1] + bv_);
                pk.z = f2bf(acc[mi][ni][2] + bv_);
                pk.w = f2bf(acc[mi][ni][3] + bv_);
                *reinterpret_cast<ushort4*>(vtout + (size_t)((bb * H_ + hh) * HD_ + dd) * SK_ + ss) = pk;
            }
        }
    }
}

// ---------------- flash attention v4: 32x32 MFMA, 32 q-rows/wave, 4-wave blocks ----
#define MFMA32(a, b, c) __builtin_amdgcn_mfma_f32_32x32x16_bf16(a, b, c, 0, 0, 0)

// softmax on S^T regs, repack to A-frags, PV into o0/o1
__device__ __forceinline__ void proc_qs(f32x16 sa, float& m_run, float& ps,
                                        f32x16& o0, f32x16& o1,
                                        const s16x8 v0a, const s16x8 v1a,
                                        const s16x8 v0b, const s16x8 v1b,
                                        const int hi, const bool lo)
{
    const float L2E = 1.44269504f;
    float a0 = fmaxf(fmaxf(sa[0], sa[1]), fmaxf(sa[2], sa[3]));
    float a1 = fmaxf(fmaxf(sa[4], sa[5]), fmaxf(sa[6], sa[7]));
    float a2 = fmaxf(fmaxf(sa[8], sa[9]), fmaxf(sa[10], sa[11]));
    float a3 = fmaxf(fmaxf(sa[12], sa[13]), fmaxf(sa[14], sa[15]));
    float pmax = fmaxf(fmaxf(a0, a1), fmaxf(a2, a3));
    if (__any(pmax > m_run + 8.f)) {            // rare: first tile + real max growth
        float mf = fmaxf(pmax, __shfl_xor(pmax, 32));
        float mn = fmaxf(m_run, mf);
        float alpha = fexp2((m_run - mn) * L2E);
        m_run = mn; ps *= alpha;
#pragma unroll
        for (int r = 0; r < 16; ++r) {
            float ar = __shfl(alpha, (r & 3) + 8 * (r >> 2) + 4 * hi);
            o0[r] *= ar; o1[r] *= ar;
        }
    }
    float ml = m_run * L2E;
    float p[16];
#pragma unroll
    for (int r = 0; r < 16; ++r) p[r] = fexp2(sa[r] * L2E - ml);
    ps += (((p[0] + p[1]) + (p[2] + p[3])) + ((p[4] + p[5]) + (p[6] + p[7]))) +
          (((p[8] + p[9]) + (p[10] + p[11])) + ((p[12] + p[13]) + (p[14] + p[15])));
    uint32_t cc[8];
#pragma unroll
    for (int j = 0; j < 8; ++j) cc[j] = pk32(p[2 * j], p[2 * j + 1]);
    uint32_t d0, d1, d2, d3, e0, e1, e2, e3;
    xch(cc[0], cc[2], lo, d0, d2);
    xch(cc[1], cc[3], lo, d1, d3);
    xch(cc[4], cc[6], lo, e0, e2);
    xch(cc[5], cc[7], lo, e1, e3);
    union { uint32_t u[4]; s16x8 v; } ua, ub;
    ua.u[0] = d0; ua.u[1] = d1; ua.u[2] = d2; ua.u[3] = d3;
    ub.u[0] = e0; ub.u[1] = e1; ub.u[2] = e2; ub.u[3] = e3;
    o0 = MFMA32(ua.v, v0a, o0);
    o0 = MFMA32(ub.v, v1a, o0);
    o1 = MFMA32(ua.v, v0b, o1);
    o1 = MFMA32(ub.v, v1b, o1);
}

__global__ __launch_bounds__(256, 3) void attn(
    const ushort* __restrict__ Qb, const ushort* __restrict__ Kb, const ushort* __restrict__ VT,
    const float* __restrict__ amask, float* __restrict__ out)
{
    __shared__ ushort Ks[2][64 * 64];   // K tile [kv][d], XOR-swizzled 128B rows
    __shared__ ushort Vs[2][64 * 64];   // V^T tile [d][kv], XOR-swizzled
    __shared__ float  Ms[1024];         // mask row for this b

    const int tid = threadIdx.x;
    const int w   = tid >> 6;           // wave 0..3: one 32-row q-subtile each
    const int l   = tid & 63;
    const int hi  = l >> 5;
    const int l31 = l & 31;
    const bool lo = (hi == 0);
    const int swz = (l31 & 7) << 4;
    const int q0w = blockIdx.x * 128 + w * 32;
    const int h = blockIdx.y, b = blockIdx.z;

    ((float4*)Ms)[tid] = ((const float4*)(amask + b * SK_))[tid];

    // Q B-frags (4 k-slices), pre-scaled by 1/8
    s16x8 qf[4];
#pragma unroll
    for (int s = 0; s < 4; ++s) {
        const ushort* gq = Qb + (size_t)(b * SQ_ + q0w + l31) * D_ + h * HD_ + s * 16 + hi * 8;
        s16x8 v = *(const s16x8*)gq;
#pragma unroll
        for (int i = 0; i < 8; ++i) v[i] = (short)f2bf(bf2f((ushort)v[i]) * 0.125f);
        qf[s] = v;
    }

    // staging: thread -> rows {row0, row0+32}, 16B chunk c8
    const int row0 = tid >> 3, c8 = tid & 7;
    const int ldsoff = row0 * 128 + ((c8 * 16) ^ ((row0 & 7) << 4));  // (row+32)&7 == row&7
    const ushort* kp = Kb + (size_t)(b * SK_ + row0) * D_ + h * HD_ + c8 * 8;
    const ushort* vp = VT + (size_t)((b * H_ + h) * HD_ + row0) * SK_ + c8 * 8;

    // prologue: tile 0 -> buffer 0
    {
        *(uint4*)((char*)Ks[0] + ldsoff)        = *(const uint4*)(kp);
        *(uint4*)((char*)Ks[0] + ldsoff + 4096) = *(const uint4*)(kp + 32 * D_);
        *(uint4*)((char*)Vs[0] + ldsoff)        = *(const uint4*)(vp);
        *(uint4*)((char*)Vs[0] + ldsoff + 4096) = *(const uint4*)(vp + 32 * SK_);
        kp += 64 * D_; vp += 64;
    }
    __syncthreads();

    f32x16 o[2];
#pragma unroll
    for (int db = 0; db < 2; ++db)
#pragma unroll
        for (int r = 0; r < 16; ++r) o[db][r] = 0.f;
    float m_run = -INFINITY, ps = 0.f;

#define TILE(CUR, NXT, T)                                                              \
    {                                                                                  \
        uint4 nk0 = *(const uint4*)(kp);                                               \
        uint4 nk1 = *(const uint4*)(kp + 32 * D_);                                     \
        uint4 nv0 = *(const uint4*)(vp);                                               \
        uint4 nv1 = *(const uint4*)(vp + 32 * SK_);                                    \
        if ((T) < 14) { kp += 64 * D_; vp += 64; }                                     \
        _Pragma("unroll")                                                              \
        for (int blk = 0; blk < 2; ++blk) {                                            \
            const int kvb = (T) * 64 + blk * 32;                                       \
            union { f32x4 q[4]; f32x16 v; } mku;                                       \
            _Pragma("unroll")                                                          \
            for (int t = 0; t < 4; ++t)                                                \
                mku.q[t] = *(const f32x4*)&Ms[kvb + 4 * hi + 8 * t];                   \
            s16x8 kfr[4];                                                              \
            _Pragma("unroll")                                                          \
            for (int s = 0; s < 4; ++s)                                                \
                kfr[s] = *(const s16x8*)((const char*)Ks[CUR] + (blk * 32 + l31) * 128 \
                                         + ((s * 32 + hi * 16) ^ swz));                \
            s16x8 vfr[2][2];                                                           \
            _Pragma("unroll")                                                          \
            for (int sl = 0; sl < 2; ++sl)                                             \
                _Pragma("unroll")                                                      \
                for (int db = 0; db < 2; ++db)                                         \
                    vfr[sl][db] = *(const s16x8*)((const char*)Vs[CUR] +               \
                        (db * 32 + l31) * 128 + ((blk * 64 + sl * 32 + hi * 16) ^ swz)); \
            f32x16 sa = MFMA32(kfr[0], qf[0], mku.v);                                  \
            sa = MFMA32(kfr[1], qf[1], sa);                                            \
            sa = MFMA32(kfr[2], qf[2], sa);                                            \
            sa = MFMA32(kfr[3], qf[3], sa);                                            \
            proc_qs(sa, m_run, ps, o[0], o[1],                                         \
                    vfr[0][0], vfr[1][0], vfr[0][1], vfr[1][1], hi, lo);               \
        }                                                                              \
        *(uint4*)((char*)Ks[NXT] + ldsoff)        = nk0;                               \
        *(uint4*)((char*)Ks[NXT] + ldsoff + 4096) = nk1;                               \
        *(uint4*)((char*)Vs[NXT] + ldsoff)        = nv0;                               \
        *(uint4*)((char*)Vs[NXT] + ldsoff + 4096) = nv1;                               \
        __syncthreads();                                                               \
    }

    for (int tt = 0; tt < 8; ++tt) {
        TILE(0, 1, 2 * tt)
        TILE(1, 0, 2 * tt + 1)
    }
#undef TILE

    // epilogue: row-sum across hi halves, normalize, write f32
    float pf = ps + __shfl_xor(ps, 32);
    float inv = 1.f / pf;
#pragma unroll
    for (int r = 0; r < 16; ++r) {
        int qr = (r & 3) + 8 * (r >> 2) + 4 * hi;
        float iv = __shfl(inv, qr);
        float* op = out + (size_t)(b * SQ_ + q0w + qr) * D_ + h * HD_ + l31;
        op[0]  = o[0][r] * iv;
        op[32] = o[1][r] * iv;
    }
}

extern "C" void kernel_launch(void* const* d_in, const int* in_sizes, int n_in,
                              void* d_out, int out_size, void* d_ws, size_t ws_size,
                              hipStream_t stream) {
    (void)in_sizes; (void)n_in; (void)out_size; (void)ws_size;
    const float* hidden  = (const float*)d_in[0];
    const float* context = (const float*)d_in[1];
    const float* amask   = (const float*)d_in[2];
    const float* Wq = (const float*)d_in[3];
    const float* bq = (const float*)d_in[4];
    const float* Wk = (const float*)d_in[5];
    const float* bk = (const float*)d_in[6];
    const float* Wv = (const float*)d_in[7];
    const float* bv = (const float*)d_in[8];
    float* out = (float*)d_out;

    char* ws = (char*)d_ws;
    ushort* hb  = (ushort*)(ws);              // 12.6 MB  hidden bf16 [8192][768]
    ushort* cb  = (ushort*)(ws + 12582912);   // 12.6 MB  context bf16
    ushort* wqt = (ushort*)(ws + 25165824);   // 1.18 MB  Wq^T bf16 [768][768]
    ushort* wkt = (ushort*)(ws + 26345472);
    ushort* wvt = (ushort*)(ws + 27525120);
    ushort* qb  = (ushort*)(ws + 28704768);   // 12.6 MB  Q bf16 [8192][768]
    ushort* kb  = (ushort*)(ws + 41287680);   // 12.6 MB  K bf16 [8192][768]
    ushort* vt  = (ushort*)(ws + 53870592);   // 12.6 MB  V^T bf16 [B][H][64][1024]
    // total 66,453,504 bytes

    int n4 = (B_ * SQ_ * D_) / 4;
    convX<<<2048, 256, 0, stream>>>((const float4*)hidden, hb, n4);
    convX<<<2048, 256, 0, stream>>>((const float4*)context, cb, n4);
    dim3 gw(24, 24);
    convWT<<<gw, 256, 0, stream>>>(Wq, wqt);
    convWT<<<gw, 256, 0, stream>>>(Wk, wkt);
    convWT<<<gw, 256, 0, stream>>>(Wv, wvt);
    gemm_qkv<<<dim3(64, 6, 3), 256, 0, stream>>>(hb, cb, wqt, wkt, wvt, bq, bk, bv, qb, kb, vt);
    attn<<<dim3(8, 12, 8), 256, 0, stream>>>(qb, kb, vt, amask, out);
}

// Round 7
// 216.424 us; speedup vs baseline: 1.2134x; 1.0103x over previous
//
#include <hip/hip_runtime.h>
#include <hip/hip_bf16.h>
#include <cstdint>

#define B_  8
#define SQ_ 1024
#define SK_ 1024
#define D_  768
#define H_  12
#define HD_ 64

typedef __attribute__((ext_vector_type(8))) short s16x8;
typedef __attribute__((ext_vector_type(4))) float f32x4;
typedef __attribute__((ext_vector_type(16))) float f32x16;

__device__ __forceinline__ float bf2f(ushort u) {
    union { uint32_t i; float f; } v; v.i = ((uint32_t)u) << 16; return v.f;
}
__device__ __forceinline__ ushort f2bf(float f) {
    __hip_bfloat16 h = __float2bfloat16(f);
    union { __hip_bfloat16 h; ushort u; } v; v.h = h; return v.u;
}
__device__ __forceinline__ uint32_t pk32(float a, float b) {
    return (uint32_t)f2bf(a) | ((uint32_t)f2bf(b) << 16);
}
__device__ __forceinline__ float fexp2(float x) {
#if __has_builtin(__builtin_amdgcn_exp2f)
    return __builtin_amdgcn_exp2f(x);
#else
    return exp2f(x);
#endif
}
// exchange across lane+-32: x = [a_lo, b_lo], y = [a_hi, b_hi]
__device__ __forceinline__ void xch(uint32_t a, uint32_t b, bool lo, uint32_t& x, uint32_t& y) {
    uint32_t bx = (uint32_t)__shfl_xor((int)b, 32);
    uint32_t ax = (uint32_t)__shfl_xor((int)a, 32);
    x = lo ? a : bx;
    y = lo ? ax : b;
}

// ---------------- merged conversions: 3x W^T + hidden/context f32->bf16 ----------------
// blocks [0,1728): W^T tiles (3 x 576); blocks [1728,...): grid-stride convX over hb||cb
__global__ void convAll(const float4* __restrict__ hsrc, const float4* __restrict__ csrc,
                        ushort* __restrict__ hb, ushort* __restrict__ cb,
                        const float* __restrict__ Wq, const float* __restrict__ Wk,
                        const float* __restrict__ Wv,
                        ushort* __restrict__ wqt, ushort* __restrict__ wkt,
                        ushort* __restrict__ wvt, int n4) {
    const int bid = blockIdx.x;
    if (bid < 1728) {
        __shared__ float t[32][33];
        const int which = bid / 576, tt = bid % 576;
        const float* W = (which == 0) ? Wq : (which == 1) ? Wk : Wv;
        ushort* WT     = (which == 0) ? wqt : (which == 1) ? wkt : wvt;
        const int k0 = (tt % 24) * 32, n0 = (tt / 24) * 32;
        const int tx = threadIdx.x & 31, ty = threadIdx.x >> 5;  // 32 x 8
#pragma unroll
        for (int rr = 0; rr < 4; ++rr)
            t[ty + 8 * rr][tx] = W[(size_t)(k0 + ty + 8 * rr) * D_ + n0 + tx];
        __syncthreads();
#pragma unroll
        for (int rr = 0; rr < 4; ++rr)
            WT[(size_t)(n0 + ty + 8 * rr) * D_ + k0 + tx] = f2bf(t[tx][ty + 8 * rr]);
    } else {
        const int n2 = 2 * n4;
        int i = (bid - 1728) * 256 + threadIdx.x;
        const int stride = (gridDim.x - 1728) * 256;
        for (; i < n2; i += stride) {
            const bool first = (i < n4);
            const int ii = first ? i : i - n4;
            float4 v = first ? hsrc[ii] : csrc[ii];
            ushort4 o = { f2bf(v.x), f2bf(v.y), f2bf(v.z), f2bf(v.w) };
            *reinterpret_cast<ushort4*>((first ? hb : cb) + (size_t)ii * 4) = o;
        }
    }
}

// ---------------- QKV GEMM v2: 2-phase double-buffered, source-swizzled LDS ----------------
#define GL16(g, l)                                                                     \
    __builtin_amdgcn_global_load_lds((const __attribute__((address_space(1))) void*)(g), \
                                     (__attribute__((address_space(3))) void*)(l), 16, 0, 0)

__global__ __launch_bounds__(256) void gemm_qkv(
    const ushort* __restrict__ hb, const ushort* __restrict__ cb,
    const ushort* __restrict__ wqt, const ushort* __restrict__ wkt, const ushort* __restrict__ wvt,
    const float* __restrict__ bq, const float* __restrict__ bk, const float* __restrict__ bv,
    ushort* __restrict__ qout, ushort* __restrict__ kout, ushort* __restrict__ vtout)
{
    const int z = blockIdx.z;
    const ushort* A    = (z == 0) ? hb : cb;
    const ushort* Wt   = (z == 0) ? wqt : (z == 1) ? wkt : wvt;
    const float*  bias = (z == 0) ? bq  : (z == 1) ? bk  : bv;

    __shared__ ushort As[2][128 * 32];
    __shared__ ushort Bs[2][128 * 32];

    const int tid = threadIdx.x;
    const int w = tid >> 6, l = tid & 63;
    const int g = l >> 4, c = l & 15;
    const int wr = w >> 1, wc = w & 1;
    const int m0 = blockIdx.x * 128;
    const int n0 = blockIdx.y * 128;
    const int c3 = c & 3;                 // frag-read swizzle key (row&3 == c&3)

    f32x4 acc[4][4];
#pragma unroll
    for (int mi = 0; mi < 4; ++mi)
#pragma unroll
        for (int ni = 0; ni < 4; ++ni) acc[mi][ni] = (f32x4){0.f, 0.f, 0.f, 0.f};

    // staging geometry: LDS chunk cc = (j*4+w)*64 + l -> row = cc>>2, pos = cc&3.
    // LDS cell (row,pos) holds GLOBAL chunk (pos ^ (row&3))  [involution, rule #21]
#define STAGE(BUF, KT)                                                                 \
    {                                                                                  \
        _Pragma("unroll")                                                              \
        for (int j = 0; j < 2; ++j) {                                                  \
            int cc = (j * 4 + w) * 64 + l;                                             \
            int row = cc >> 2;                                                         \
            int gc = (cc & 3) ^ (row & 3);                                             \
            GL16(A  + (size_t)(m0 + row) * D_ + (KT) * 32 + gc * 8,                    \
                 (char*)As[BUF] + (size_t)(j * 4 + w) * 1024);                         \
            GL16(Wt + (size_t)(n0 + row) * D_ + (KT) * 32 + gc * 8,                    \
                 (char*)Bs[BUF] + (size_t)(j * 4 + w) * 1024);                         \
        }                                                                              \
    }

    STAGE(0, 0)
    __syncthreads();

    int cur = 0;
    for (int kt = 0; kt < D_ / 32; ++kt) {
        if (kt < D_ / 32 - 1) STAGE(cur ^ 1, kt + 1)

        s16x8 af[4], bfr[4];
#pragma unroll
        for (int mi = 0; mi < 4; ++mi)
            af[mi] = *(const s16x8*)((const char*)As[cur] +
                                     (wr * 64 + mi * 16 + c) * 64 + ((g ^ c3) << 4));
#pragma unroll
        for (int ni = 0; ni < 4; ++ni)
            bfr[ni] = *(const s16x8*)((const char*)Bs[cur] +
                                      (wc * 64 + ni * 16 + c) * 64 + ((g ^ c3) << 4));
#pragma unroll
        for (int mi = 0; mi < 4; ++mi)
#pragma unroll
            for (int ni = 0; ni < 4; ++ni)
                acc[mi][ni] = __builtin_amdgcn_mfma_f32_16x16x32_bf16(af[mi], bfr[ni], acc[mi][ni], 0, 0, 0);

        __syncthreads();   // drains the STAGE loads (issued ~full compute phase earlier)
        cur ^= 1;
    }
#undef STAGE

    if (z < 2) {
        ushort* Out = (z == 0) ? qout : kout;
#pragma unroll
        for (int ni = 0; ni < 4; ++ni) {
            int ncol = n0 + wc * 64 + ni * 16 + c;
            float bv_ = bias[ncol];
#pragma unroll
            for (int mi = 0; mi < 4; ++mi) {
#pragma unroll
                for (int r = 0; r < 4; ++r) {
                    int mrow = m0 + wr * 64 + mi * 16 + 4 * g + r;
                    Out[(size_t)mrow * D_ + ncol] = f2bf(acc[mi][ni][r] + bv_);
                }
            }
        }
    } else {
        // V: write transposed per-head: VT[((b*H + h)*HD + d)*SK + s]
#pragma unroll
        for (int ni = 0; ni < 4; ++ni) {
            int ncol = n0 + wc * 64 + ni * 16 + c;
            float bv_ = bias[ncol];
            int hh = ncol >> 6, dd = ncol & 63;
#pragma unroll
            for (int mi = 0; mi < 4; ++mi) {
                int mrow = m0 + wr * 64 + mi * 16 + 4 * g;   // 4 consecutive rows
                int bb = mrow >> 10, ss = mrow & 1023;
                ushort4 pk;
                pk.x = f2bf(acc[mi][ni][0] + bv_);
                pk.y = f2bf(acc[mi][ni][1] + bv_);
                pk.z = f2bf(acc[mi][ni][2] + bv_);
                pk.w = f2bf(acc[mi][ni][3] + bv_);
                *reinterpret_cast<ushort4*>(vtout + (size_t)((bb * H_ + hh) * HD_ + dd) * SK_ + ss) = pk;
            }
        }
    }
}

// ---------------- flash attention v4: 32x32 MFMA, 32 q-rows/wave, 4-wave blocks ----
#define MFMA32(a, b, c) __builtin_amdgcn_mfma_f32_32x32x16_bf16(a, b, c, 0, 0, 0)

// softmax on S^T regs, repack to A-frags, PV into o0/o1
__device__ __forceinline__ void proc_qs(f32x16 sa, float& m_run, float& ps,
                                        f32x16& o0, f32x16& o1,
                                        const s16x8 v0a, const s16x8 v1a,
                                        const s16x8 v0b, const s16x8 v1b,
                                        const int hi, const bool lo)
{
    const float L2E = 1.44269504f;
    float a0 = fmaxf(fmaxf(sa[0], sa[1]), fmaxf(sa[2], sa[3]));
    float a1 = fmaxf(fmaxf(sa[4], sa[5]), fmaxf(sa[6], sa[7]));
    float a2 = fmaxf(fmaxf(sa[8], sa[9]), fmaxf(sa[10], sa[11]));
    float a3 = fmaxf(fmaxf(sa[12], sa[13]), fmaxf(sa[14], sa[15]));
    float pmax = fmaxf(fmaxf(a0, a1), fmaxf(a2, a3));
    if (__any(pmax > m_run + 8.f)) {            // rare: first tile + real max growth
        float mf = fmaxf(pmax, __shfl_xor(pmax, 32));
        float mn = fmaxf(m_run, mf);
        float alpha = fexp2((m_run - mn) * L2E);
        m_run = mn; ps *= alpha;
#pragma unroll
        for (int r = 0; r < 16; ++r) {
            float ar = __shfl(alpha, (r & 3) + 8 * (r >> 2) + 4 * hi);
            o0[r] *= ar; o1[r] *= ar;
        }
    }
    float ml = m_run * L2E;
    float p[16];
#pragma unroll
    for (int r = 0; r < 16; ++r) p[r] = fexp2(sa[r] * L2E - ml);
    ps += (((p[0] + p[1]) + (p[2] + p[3])) + ((p[4] + p[5]) + (p[6] + p[7]))) +
          (((p[8] + p[9]) + (p[10] + p[11])) + ((p[12] + p[13]) + (p[14] + p[15])));
    uint32_t cc[8];
#pragma unroll
    for (int j = 0; j < 8; ++j) cc[j] = pk32(p[2 * j], p[2 * j + 1]);
    uint32_t d0, d1, d2, d3, e0, e1, e2, e3;
    xch(cc[0], cc[2], lo, d0, d2);
    xch(cc[1], cc[3], lo, d1, d3);
    xch(cc[4], cc[6], lo, e0, e2);
    xch(cc[5], cc[7], lo, e1, e3);
    union { uint32_t u[4]; s16x8 v; } ua, ub;
    ua.u[0] = d0; ua.u[1] = d1; ua.u[2] = d2; ua.u[3] = d3;
    ub.u[0] = e0; ub.u[1] = e1; ub.u[2] = e2; ub.u[3] = e3;
    o0 = MFMA32(ua.v, v0a, o0);
    o0 = MFMA32(ub.v, v1a, o0);
    o1 = MFMA32(ua.v, v0b, o1);
    o1 = MFMA32(ub.v, v1b, o1);
}

__global__ __launch_bounds__(256, 3) void attn(
    const ushort* __restrict__ Qb, const ushort* __restrict__ Kb, const ushort* __restrict__ VT,
    const float* __restrict__ amask, float* __restrict__ out)
{
    __shared__ ushort Ks[2][64 * 64];   // K tile [kv][d], XOR-swizzled 128B rows
    __shared__ ushort Vs[2][64 * 64];   // V^T tile [d][kv], XOR-swizzled
    __shared__ float  Ms[1024];         // mask row for this b

    const int tid = threadIdx.x;
    const int w   = tid >> 6;           // wave 0..3: one 32-row q-subtile each
    const int l   = tid & 63;
    const int hi  = l >> 5;
    const int l31 = l & 31;
    const bool lo = (hi == 0);
    const int swz = (l31 & 7) << 4;
    const int q0w = blockIdx.x * 128 + w * 32;
    const int h = blockIdx.y, b = blockIdx.z;

    ((float4*)Ms)[tid] = ((const float4*)(amask + b * SK_))[tid];

    // Q B-frags (4 k-slices), pre-scaled by 1/8
    s16x8 qf[4];
#pragma unroll
    for (int s = 0; s < 4; ++s) {
        const ushort* gq = Qb + (size_t)(b * SQ_ + q0w + l31) * D_ + h * HD_ + s * 16 + hi * 8;
        s16x8 v = *(const s16x8*)gq;
#pragma unroll
        for (int i = 0; i < 8; ++i) v[i] = (short)f2bf(bf2f((ushort)v[i]) * 0.125f);
        qf[s] = v;
    }

    // staging: thread -> rows {row0, row0+32}, 16B chunk c8
    const int row0 = tid >> 3, c8 = tid & 7;
    const int ldsoff = row0 * 128 + ((c8 * 16) ^ ((row0 & 7) << 4));  // (row+32)&7 == row&7
    const ushort* kp = Kb + (size_t)(b * SK_ + row0) * D_ + h * HD_ + c8 * 8;
    const ushort* vp = VT + (size_t)((b * H_ + h) * HD_ + row0) * SK_ + c8 * 8;

    // prologue: tile 0 -> buffer 0
    {
        *(uint4*)((char*)Ks[0] + ldsoff)        = *(const uint4*)(kp);
        *(uint4*)((char*)Ks[0] + ldsoff + 4096) = *(const uint4*)(kp + 32 * D_);
        *(uint4*)((char*)Vs[0] + ldsoff)        = *(const uint4*)(vp);
        *(uint4*)((char*)Vs[0] + ldsoff + 4096) = *(const uint4*)(vp + 32 * SK_);
        kp += 64 * D_; vp += 64;
    }
    __syncthreads();

    f32x16 o[2];
#pragma unroll
    for (int db = 0; db < 2; ++db)
#pragma unroll
        for (int r = 0; r < 16; ++r) o[db][r] = 0.f;
    float m_run = -INFINITY, ps = 0.f;

#define TILE(CUR, NXT, T)                                                              \
    {                                                                                  \
        uint4 nk0 = *(const uint4*)(kp);                                               \
        uint4 nk1 = *(const uint4*)(kp + 32 * D_);                                     \
        uint4 nv0 = *(const uint4*)(vp);                                               \
        uint4 nv1 = *(const uint4*)(vp + 32 * SK_);                                    \
        if ((T) < 14) { kp += 64 * D_; vp += 64; }                                     \
        _Pragma("unroll")                                                              \
        for (int blk = 0; blk < 2; ++blk) {                                            \
            const int kvb = (T) * 64 + blk * 32;                                       \
            union { f32x4 q[4]; f32x16 v; } mku;                                       \
            _Pragma("unroll")                                                          \
            for (int t = 0; t < 4; ++t)                                                \
                mku.q[t] = *(const f32x4*)&Ms[kvb + 4 * hi + 8 * t];                   \
            s16x8 kfr[4];                                                              \
            _Pragma("unroll")                                                          \
            for (int s = 0; s < 4; ++s)                                                \
                kfr[s] = *(const s16x8*)((const char*)Ks[CUR] + (blk * 32 + l31) * 128 \
                                         + ((s * 32 + hi * 16) ^ swz));                \
            s16x8 vfr[2][2];                                                           \
            _Pragma("unroll")                                                          \
            for (int sl = 0; sl < 2; ++sl)                                             \
                _Pragma("unroll")                                                      \
                for (int db = 0; db < 2; ++db)                                         \
                    vfr[sl][db] = *(const s16x8*)((const char*)Vs[CUR] +               \
                        (db * 32 + l31) * 128 + ((blk * 64 + sl * 32 + hi * 16) ^ swz)); \
            f32x16 sa = MFMA32(kfr[0], qf[0], mku.v);                                  \
            sa = MFMA32(kfr[1], qf[1], sa);                                            \
            sa = MFMA32(kfr[2], qf[2], sa);                                            \
            sa = MFMA32(kfr[3], qf[3], sa);                                            \
            proc_qs(sa, m_run, ps, o[0], o[1],                                         \
                    vfr[0][0], vfr[1][0], vfr[0][1], vfr[1][1], hi, lo);               \
        }                                                                              \
        *(uint4*)((char*)Ks[NXT] + ldsoff)        = nk0;                               \
        *(uint4*)((char*)Ks[NXT] + ldsoff + 4096) = nk1;                               \
        *(uint4*)((char*)Vs[NXT] + ldsoff)        = nv0;                               \
        *(uint4*)((char*)Vs[NXT] + ldsoff + 4096) = nv1;                               \
        __syncthreads();                                                               \
    }

    for (int tt = 0; tt < 8; ++tt) {
        TILE(0, 1, 2 * tt)
        TILE(1, 0, 2 * tt + 1)
    }
#undef TILE

    // epilogue: row-sum across hi halves, normalize, write f32
    float pf = ps + __shfl_xor(ps, 32);
    float inv = 1.f / pf;
#pragma unroll
    for (int r = 0; r < 16; ++r) {
        int qr = (r & 3) + 8 * (r >> 2) + 4 * hi;
        float iv = __shfl(inv, qr);
        float* op = out + (size_t)(b * SQ_ + q0w + qr) * D_ + h * HD_ + l31;
        op[0]  = o[0][r] * iv;
        op[32] = o[1][r] * iv;
    }
}

extern "C" void kernel_launch(void* const* d_in, const int* in_sizes, int n_in,
                              void* d_out, int out_size, void* d_ws, size_t ws_size,
                              hipStream_t stream) {
    (void)in_sizes; (void)n_in; (void)out_size; (void)ws_size;
    const float* hidden  = (const float*)d_in[0];
    const float* context = (const float*)d_in[1];
    const float* amask   = (const float*)d_in[2];
    const float* Wq = (const float*)d_in[3];
    const float* bq = (const float*)d_in[4];
    const float* Wk = (const float*)d_in[5];
    const float* bk = (const float*)d_in[6];
    const float* Wv = (const float*)d_in[7];
    const float* bv = (const float*)d_in[8];
    float* out = (float*)d_out;

    char* ws = (char*)d_ws;
    ushort* hb  = (ushort*)(ws);              // 12.6 MB  hidden bf16 [8192][768]
    ushort* cb  = (ushort*)(ws + 12582912);   // 12.6 MB  context bf16
    ushort* wqt = (ushort*)(ws + 25165824);   // 1.18 MB  Wq^T bf16 [768][768]
    ushort* wkt = (ushort*)(ws + 26345472);
    ushort* wvt = (ushort*)(ws + 27525120);
    ushort* qb  = (ushort*)(ws + 28704768);   // 12.6 MB  Q bf16 [8192][768]
    ushort* kb  = (ushort*)(ws + 41287680);   // 12.6 MB  K bf16 [8192][768]
    ushort* vt  = (ushort*)(ws + 53870592);   // 12.6 MB  V^T bf16 [B][H][64][1024]
    // total 66,453,504 bytes

    int n4 = (B_ * SQ_ * D_) / 4;
    convAll<<<1728 + 2048, 256, 0, stream>>>((const float4*)hidden, (const float4*)context,
                                             hb, cb, Wq, Wk, Wv, wqt, wkt, wvt, n4);
    gemm_qkv<<<dim3(64, 6, 3), 256, 0, stream>>>(hb, cb, wqt, wkt, wvt, bq, bk, bv, qb, kb, vt);
    attn<<<dim3(8, 12, 8), 256, 0, stream>>>(qb, kb, vt, amask, out);
}